// Round 18
// baseline (135.550 us; speedup 1.0000x reference)
//
#include <hip/hip_runtime.h>

#define NPOS 4096
#define CDIM 256
#define FDIM 64

typedef short short8 __attribute__((ext_vector_type(8)));
typedef float f32x4 __attribute__((ext_vector_type(4)));

__device__ __forceinline__ unsigned short f2bf(float v) {
  unsigned u = __float_as_uint(v);
  unsigned r = (u + 0x7fffu + ((u >> 16) & 1u)) >> 16;  // RNE
  return (unsigned short)r;
}
__device__ __forceinline__ float bf2f(unsigned short u) {
  return __uint_as_float((unsigned)u << 16);
}
__device__ __forceinline__ short8 as_s8(uint4 u) {
  return *reinterpret_cast<short8*>(&u);
}
__device__ __forceinline__ void gload_lds16(const void* g, void* l) {
  __builtin_amdgcn_global_load_lds(
      (const __attribute__((address_space(1))) unsigned int*)g,
      (__attribute__((address_space(3))) unsigned int*)l, 16, 0, 0);
}

// ---------------------------------------------------------------------------
// Kernel 1: projections + out = x init (unchanged).
// ---------------------------------------------------------------------------
__global__ __launch_bounds__(256) void proj_kernel(
    const float* __restrict__ x, const float* __restrict__ Wf,
    const float* __restrict__ Wg, const float* __restrict__ Wh,
    unsigned short* __restrict__ f_hi, unsigned short* __restrict__ f_lo,
    unsigned short* __restrict__ g_hi, unsigned short* __restrict__ g_lo,
    unsigned short* __restrict__ h_t, float* __restrict__ out) {
  __shared__ float xs[16][CDIM];
  const int row0 = blockIdx.x * 16;
  const int t = threadIdx.x;
  {
    const float4* xv = reinterpret_cast<const float4*>(x + (size_t)row0 * CDIM);
    float4* sv = reinterpret_cast<float4*>(&xs[0][0]);
    float4* ov = reinterpret_cast<float4*>(out + (size_t)row0 * CDIM);
#pragma unroll
    for (int i = 0; i < 4; ++i) {
      const float4 v = xv[t + 256 * i];
      sv[t + 256 * i] = v;
      ov[t + 256 * i] = v;   // out = x (PV partial sums atomically added later)
    }
  }
  __syncthreads();
  {
    float acc[16];
#pragma unroll
    for (int r = 0; r < 16; ++r) acc[r] = 0.f;
    for (int k = 0; k < CDIM; k += 4) {
      const float w0 = Wh[(size_t)(k + 0) * CDIM + t];
      const float w1 = Wh[(size_t)(k + 1) * CDIM + t];
      const float w2 = Wh[(size_t)(k + 2) * CDIM + t];
      const float w3 = Wh[(size_t)(k + 3) * CDIM + t];
#pragma unroll
      for (int r = 0; r < 16; ++r) {
        const float4 xv = *reinterpret_cast<const float4*>(&xs[r][k]);
        float a = acc[r];
        a = fmaf(xv.x, w0, a);
        a = fmaf(xv.y, w1, a);
        a = fmaf(xv.z, w2, a);
        a = fmaf(xv.w, w3, a);
        acc[r] = a;
      }
    }
    const int b = row0 >> 12;
    const int lr = row0 & (NPOS - 1);
    unsigned wd[8];
#pragma unroll
    for (int i = 0; i < 8; ++i)
      wd[i] = (unsigned)f2bf(acc[2 * i]) | ((unsigned)f2bf(acc[2 * i + 1]) << 16);
    uint4* base = reinterpret_cast<uint4*>(h_t + ((size_t)(b * CDIM + t)) * NPOS);
    const int m = t & 7;
    const int c0 = lr >> 3;   // even
    base[c0 ^ m] = make_uint4(wd[0], wd[1], wd[2], wd[3]);
    base[(c0 + 1) ^ m] = make_uint4(wd[4], wd[5], wd[6], wd[7]);
  }
  {
    const int col = t & 63;
    const int rb = (t >> 6) * 4;
    const int colq = col >> 3, cwi = col & 7;
    float af[4] = {0.f, 0.f, 0.f, 0.f};
    float ag[4] = {0.f, 0.f, 0.f, 0.f};
    for (int k = 0; k < CDIM; k += 4) {
      const float wf0 = Wf[(size_t)(k + 0) * FDIM + col];
      const float wf1 = Wf[(size_t)(k + 1) * FDIM + col];
      const float wf2 = Wf[(size_t)(k + 2) * FDIM + col];
      const float wf3 = Wf[(size_t)(k + 3) * FDIM + col];
      const float wg0 = Wg[(size_t)(k + 0) * FDIM + col];
      const float wg1 = Wg[(size_t)(k + 1) * FDIM + col];
      const float wg2 = Wg[(size_t)(k + 2) * FDIM + col];
      const float wg3 = Wg[(size_t)(k + 3) * FDIM + col];
#pragma unroll
      for (int r = 0; r < 4; ++r) {
        const float4 xv = *reinterpret_cast<const float4*>(&xs[rb + r][k]);
        float a = af[r], bb = ag[r];
        a = fmaf(xv.x, wf0, a); a = fmaf(xv.y, wf1, a);
        a = fmaf(xv.z, wf2, a); a = fmaf(xv.w, wf3, a);
        bb = fmaf(xv.x, wg0, bb); bb = fmaf(xv.y, wg1, bb);
        bb = fmaf(xv.z, wg2, bb); bb = fmaf(xv.w, wg3, bb);
        af[r] = a; ag[r] = bb;
      }
    }
#pragma unroll
    for (int r = 0; r < 4; ++r) {
      const int row = row0 + rb + r;
      const int ph = ((colq ^ (row & 7)) << 3) | cwi;
      const size_t of = (size_t)row * FDIM + ph;
      const size_t og = (size_t)row * FDIM + col;
      const unsigned short fh = f2bf(af[r]);
      const unsigned short gh = f2bf(ag[r]);
      f_hi[of] = fh;
      f_lo[of] = f2bf(af[r] - bf2f(fh));
      g_hi[og] = gh;
      g_lo[og] = f2bf(ag[r] - bf2f(gh));
    }
  }
}

// ---------------------------------------------------------------------------
// Kernel 2A (unchanged from r17): 16 fat iterations, 256-col f tiles.
// ---------------------------------------------------------------------------
__global__ __launch_bounds__(1024, 4) void qk_l_kernel(
    const unsigned short* __restrict__ f_hi, const unsigned short* __restrict__ f_lo,
    const unsigned short* __restrict__ g_hi, const unsigned short* __restrict__ g_lo,
    unsigned short* __restrict__ Pws, float* __restrict__ lrow) {
  __shared__ uint4 Fh[2][256][8];   // 64 KB
  __shared__ uint4 Fl[2][256][8];   // 64 KB
  __shared__ float partl[16][32];

  const int wg = blockIdx.x;
  const int wgid = (wg & 7) * 32 + (wg >> 3);   // bijective XCD chunking (256 wgs)
  const int b = wgid >> 7;
  const int row0 = (wgid & 127) * 32;
  const int t = threadIdx.x;
  const int w = t >> 6;     // 0..15: col strip w*16
  const int l = t & 63;
  const int lr = l & 15;
  const int lk = l >> 4;

  short8 gh0[2], gl0[2], gh1[2], gl1[2];
  {
    const unsigned short* gH0 = g_hi + ((size_t)(b * NPOS + row0 + lr)) * FDIM + lk * 8;
    const unsigned short* gL0 = g_lo + ((size_t)(b * NPOS + row0 + lr)) * FDIM + lk * 8;
    const unsigned short* gH1 = gH0 + (size_t)16 * FDIM;
    const unsigned short* gL1 = gL0 + (size_t)16 * FDIM;
#pragma unroll
    for (int ks = 0; ks < 2; ++ks) {
      gh0[ks] = *reinterpret_cast<const short8*>(gH0 + ks * 32);
      gl0[ks] = *reinterpret_cast<const short8*>(gL0 + ks * 32);
      gh1[ks] = *reinterpret_cast<const short8*>(gH1 + ks * 32);
      gl1[ks] = *reinterpret_cast<const short8*>(gL1 + ks * 32);
    }
  }
  const unsigned short* fbh = f_hi + (size_t)b * NPOS * FDIM;
  const unsigned short* fbl = f_lo + (size_t)b * NPOS * FDIM;
  unsigned short* prow0 = Pws + (size_t)(b * NPOS + row0 + lr) * NPOS;
  unsigned short* prow1 = prow0 + (size_t)16 * NPOS;
  const int rsw = lr & 7;
  float lsum0 = 0.f, lsum1 = 0.f;

#define STAGEA(buf, tile)                                                      \
  do {                                                                         \
    _Pragma("unroll")                                                          \
    for (int j = 0; j < 2; ++j) {                                              \
      const int slot_ = j * 1024 + t;                                          \
      const int row_ = slot_ >> 3, ch_ = slot_ & 7;                            \
      gload_lds16(fbh + (size_t)((tile) * 256 + row_) * FDIM + ch_ * 8,        \
                  (char*)&Fh[buf][0][0] + (size_t)slot_ * 16);                 \
      gload_lds16(fbl + (size_t)((tile) * 256 + row_) * FDIM + ch_ * 8,        \
                  (char*)&Fl[buf][0][0] + (size_t)slot_ * 16);                 \
    }                                                                          \
  } while (0)

  STAGEA(0, 0);
  asm volatile("s_waitcnt vmcnt(0) lgkmcnt(0)\ns_barrier" ::: "memory");

  const int rrA = w * 16 + lr;
  const int fsw = rrA & 7;
  int buf = 0;
  for (int tile = 0; tile < 16; ++tile) {
    if (tile < 15) STAGEA(buf ^ 1, tile + 1);
    __builtin_amdgcn_sched_barrier(0);   // pin gloads at top (vmcnt count safety)
    const uint4 h0 = Fh[buf][rrA][lk ^ fsw];
    const uint4 h1 = Fh[buf][rrA][(lk + 4) ^ fsw];
    const uint4 q0 = Fl[buf][rrA][lk ^ fsw];
    const uint4 q1 = Fl[buf][rrA][(lk + 4) ^ fsw];
    // ---- row-half 0
    {
      f32x4 acca = {0.f, 0.f, 0.f, 0.f};
      f32x4 accb = {0.f, 0.f, 0.f, 0.f};
      acca = __builtin_amdgcn_mfma_f32_16x16x32_bf16(as_s8(h0), gh0[0], acca, 0, 0, 0);
      accb = __builtin_amdgcn_mfma_f32_16x16x32_bf16(as_s8(h0), gl0[0], accb, 0, 0, 0);
      acca = __builtin_amdgcn_mfma_f32_16x16x32_bf16(as_s8(q0), gh0[0], acca, 0, 0, 0);
      accb = __builtin_amdgcn_mfma_f32_16x16x32_bf16(as_s8(h1), gh0[1], accb, 0, 0, 0);
      acca = __builtin_amdgcn_mfma_f32_16x16x32_bf16(as_s8(q1), gh0[1], acca, 0, 0, 0);
      accb = __builtin_amdgcn_mfma_f32_16x16x32_bf16(as_s8(h1), gl0[1], accb, 0, 0, 0);
      const f32x4 acc = acca + accb;
      const int cq = tile * 256 + w * 16 + lk * 4;
      const float e0 = __expf(acc[0]);
      const float e1 = __expf(acc[1]);
      const float e2 = __expf(acc[2]);
      const float e3 = __expf(acc[3]);
      lsum0 += (e0 + e1) + (e2 + e3);
      uint2 pk;
      pk.x = (unsigned)f2bf(e0) | ((unsigned)f2bf(e1) << 16);
      pk.y = (unsigned)f2bf(e2) | ((unsigned)f2bf(e3) << 16);
      const int sidx = (((cq >> 3) ^ rsw) << 3) | (cq & 7);
      *reinterpret_cast<uint2*>(prow0 + sidx) = pk;
    }
    // ---- row-half 1
    {
      f32x4 acca = {0.f, 0.f, 0.f, 0.f};
      f32x4 accb = {0.f, 0.f, 0.f, 0.f};
      acca = __builtin_amdgcn_mfma_f32_16x16x32_bf16(as_s8(h0), gh1[0], acca, 0, 0, 0);
      accb = __builtin_amdgcn_mfma_f32_16x16x32_bf16(as_s8(h0), gl1[0], accb, 0, 0, 0);
      acca = __builtin_amdgcn_mfma_f32_16x16x32_bf16(as_s8(q0), gh1[0], acca, 0, 0, 0);
      accb = __builtin_amdgcn_mfma_f32_16x16x32_bf16(as_s8(h1), gh1[1], accb, 0, 0, 0);
      acca = __builtin_amdgcn_mfma_f32_16x16x32_bf16(as_s8(q1), gh1[1], acca, 0, 0, 0);
      accb = __builtin_amdgcn_mfma_f32_16x16x32_bf16(as_s8(h1), gl1[1], accb, 0, 0, 0);
      const f32x4 acc = acca + accb;
      const int cq = tile * 256 + w * 16 + lk * 4;
      const float e0 = __expf(acc[0]);
      const float e1 = __expf(acc[1]);
      const float e2 = __expf(acc[2]);
      const float e3 = __expf(acc[3]);
      lsum1 += (e0 + e1) + (e2 + e3);
      uint2 pk;
      pk.x = (unsigned)f2bf(e0) | ((unsigned)f2bf(e1) << 16);
      pk.y = (unsigned)f2bf(e2) | ((unsigned)f2bf(e3) << 16);
      const int sidx = (((cq >> 3) ^ rsw) << 3) | (cq & 7);
      *reinterpret_cast<uint2*>(prow1 + sidx) = pk;
    }
    asm volatile("s_waitcnt vmcnt(2) lgkmcnt(0)\ns_barrier" ::: "memory");
    buf ^= 1;
  }
#undef STAGEA

  lsum0 += __shfl_xor(lsum0, 16);
  lsum0 += __shfl_xor(lsum0, 32);
  lsum1 += __shfl_xor(lsum1, 16);
  lsum1 += __shfl_xor(lsum1, 32);
  if (l < 16) {
    partl[w][l] = lsum0;
    partl[w][16 + l] = lsum1;
  }
  __syncthreads();
  if (t < 32) {
    float s = 0.f;
#pragma unroll
    for (int q = 0; q < 16; ++q) s += partl[q][t];
    lrow[(size_t)b * NPOS + row0 + t] = s;
  }
}

// ---------------------------------------------------------------------------
// Kernel 2B (v2: HALVED barrier count): beta = P/l (fp32, its K-quarter) +
// o_partial = beta @ h atomically added into out.
// Block = 128 beta-rows x 256 cols x K-quarter(1024), 1024 threads / 16 waves,
// grid 256 (32 row-tiles x 2 b x 4 K-quarters) -> 16 iterations (was 32),
// and staged h_t bytes drop 320 -> 192 MB.
// Per iter: 3 gloads/thread (Ab 1 + Bb 2), 16 MFMAs/wave, 2 float4 beta
// writes/thread; counted barrier vmcnt(2) (own beta stores stay in flight).
// ---------------------------------------------------------------------------
__global__ __launch_bounds__(1024, 4) void pv_split_kernel(
    const unsigned short* __restrict__ h_t, const unsigned short* __restrict__ Pws,
    const float* __restrict__ lrow, const float* __restrict__ gamma,
    float* __restrict__ beta, float* __restrict__ out) {
  __shared__ uint4 Ab[2][128][8];    // P tile  [128 r][8 chunks] 16 KiB/buf
  __shared__ uint4 Bb[2][256][8];    // h tile  [256 c][8 chunks] 32 KiB/buf
  __shared__ float linvB[128];

  const int wg = blockIdx.x;
  const int wgid = (wg & 7) * 32 + (wg >> 3);   // bijective XCD chunking (256 wgs)
  const int b = wgid >> 7;
  const int kq = (wgid >> 5) & 3;
  const int row0 = (wgid & 31) * 128;
  const int t = threadIdx.x;
  const int w = t >> 6;
  const int l = t & 63;
  const int lr = l & 15;
  const int lk = l >> 4;

  if (t < 128) linvB[t] = __frcp_rn(lrow[(size_t)b * NPOS + row0 + t]);

  const size_t hoff = (size_t)b * CDIM * NPOS;
  const unsigned short* Pb = Pws + (size_t)(b * NPOS + row0) * NPOS;
  const int kbase = kq * 128;        // physical 16B-chunk base of this K-quarter

#define STAGEB(bufi, kt)                                                        \
  do {                                                                          \
    _Pragma("unroll")                                                           \
    for (int j = 0; j < 2; ++j) {                                               \
      const int slot_ = j * 1024 + t;                                           \
      const int col_ = slot_ >> 3, ch_ = slot_ & 7;                             \
      const unsigned short* g_ = h_t + hoff + (size_t)col_ * NPOS +             \
                                 (size_t)(kbase + (kt) * 8 + ch_) * 8;          \
      gload_lds16(g_, (char*)&Bb[bufi][0][0] + (size_t)slot_ * 16);             \
    }                                                                           \
    {                                                                           \
      const int row_ = t >> 3, ch_ = t & 7;                                     \
      const unsigned short* g_ = Pb + (size_t)row_ * NPOS +                     \
                                 (size_t)(kbase + (kt) * 8 + ch_) * 8;          \
      gload_lds16(g_, (char*)&Ab[bufi][0][0] + (size_t)t * 16);                 \
    }                                                                           \
  } while (0)

  f32x4 acc[8];
#pragma unroll
  for (int c = 0; c < 8; ++c) acc[c] = (f32x4){0.f, 0.f, 0.f, 0.f};
  const int wrB = w & 7;               // row octet (0..7)
  const int wcB = w >> 3;              // col half of 128 (0/1)
  const int arB = wrB * 16 + lr;       // local A row 0..127
  const int cbase = wcB * 128 + lr;
  const int brow = t >> 3;             // beta-write row 0..127
  const int jjb = t & 7;               // float4 indices jjb, jjb+8 of 16

  STAGEB(0, 0);
  asm volatile("s_waitcnt vmcnt(0) lgkmcnt(0)\ns_barrier" ::: "memory");
  const float il_brow = linvB[brow];

  int buf = 0;
  for (int kt = 0; kt < 16; ++kt) {
    if (kt < 15) STAGEB(buf ^ 1, kt + 1);
    __builtin_amdgcn_sched_barrier(0);   // pin gloads at top (vmcnt count safety)
    // ---- MFMA: K=64 as 2 k-steps of 32, 8 col-tiles per wave
    {
      const uint4 a0 = Ab[buf][arB][lk ^ (arB & 7)];
      const uint4 a1 = Ab[buf][arB][(4 + lk) ^ (arB & 7)];
#pragma unroll
      for (int c = 0; c < 8; ++c) {
        const int cc = cbase + 16 * c;
        const uint4 b0 = Bb[buf][cc][lk ^ (cc & 7)];
        acc[c] = __builtin_amdgcn_mfma_f32_16x16x32_bf16(as_s8(a0), as_s8(b0),
                                                         acc[c], 0, 0, 0);
      }
#pragma unroll
      for (int c = 0; c < 8; ++c) {
        const int cc = cbase + 16 * c;
        const uint4 b1 = Bb[buf][cc][(4 + lk) ^ (cc & 7)];
        acc[c] = __builtin_amdgcn_mfma_f32_16x16x32_bf16(as_s8(a1), as_s8(b1),
                                                         acc[c], 0, 0, 0);
      }
    }
    // ---- beta write: two float4/thread from staged A tile (swizzled read)
#pragma unroll
    for (int q = 0; q < 2; ++q) {
      const int jj = jjb + q * 8;
      const uint4 u4 = Ab[buf][brow][(jj >> 1) ^ (brow & 7)];
      const uint2 u = (jj & 1) ? make_uint2(u4.z, u4.w) : make_uint2(u4.x, u4.y);
      float4 v;
      v.x = bf2f((unsigned short)(u.x & 0xffffu)) * il_brow;
      v.y = bf2f((unsigned short)(u.x >> 16)) * il_brow;
      v.z = bf2f((unsigned short)(u.y & 0xffffu)) * il_brow;
      v.w = bf2f((unsigned short)(u.y >> 16)) * il_brow;
      *reinterpret_cast<float4*>(beta + (size_t)(b * NPOS + row0 + brow) * NPOS +
                                 kq * 1024 + kt * 64 + jj * 4) = v;
    }
    // counted barrier: drain this iter's 3 gloads; own 2 beta-stores in flight
    asm volatile("s_waitcnt vmcnt(2) lgkmcnt(0)\ns_barrier" ::: "memory");
    buf ^= 1;
  }
#undef STAGEB

  // epilogue: atomically add partial gamma*o/l into out (= x + all quarters)
  const float gam = gamma[0];
#pragma unroll
  for (int r = 0; r < 4; ++r) {
    const int lrr = wrB * 16 + lk * 4 + r;
    const int orow = row0 + lrr;
    const float sc = gam * linvB[lrr];
    float* o = out + ((size_t)b * NPOS + orow) * CDIM + cbase;
#pragma unroll
    for (int c = 0; c < 8; ++c) atomicAdd(o + 16 * c, sc * acc[c][r]);
  }
}

// ---------------------------------------------------------------------------
// FALLBACK (if ws too small for Pws): r14 fused kernel, P inside beta rows.
// ---------------------------------------------------------------------------
__global__ __launch_bounds__(1024, 4) void attn_fused_kernel(
    const unsigned short* __restrict__ f_hi, const unsigned short* __restrict__ f_lo,
    const unsigned short* __restrict__ g_hi, const unsigned short* __restrict__ g_lo,
    const unsigned short* __restrict__ h_t, const float* __restrict__ x,
    const float* __restrict__ gamma, float* __restrict__ beta,
    float* __restrict__ out) {
  __shared__ __align__(16) char shraw[110592];
  __shared__ float partl[16][16];
  __shared__ float linvs[32];
  uint4 (*Fh)[128][8] = reinterpret_cast<uint4(*)[128][8]>(shraw);
  uint4 (*Fl)[128][8] = reinterpret_cast<uint4(*)[128][8]>(shraw + 32768);
  uint4 (*Ab)[32][8] = reinterpret_cast<uint4(*)[32][8]>(shraw);
  uint4 (*Bb)[256][8] = reinterpret_cast<uint4(*)[256][8]>(shraw + 12288);

  const int wg = blockIdx.x;
  const int wgid = (wg & 7) * 32 + (wg >> 3);
  const int b = wgid >> 7;
  const int row0 = (wgid & 127) * 32;
  const int t = threadIdx.x;
  const int w = t >> 6;
  const int l = t & 63;
  const int lr = l & 15;
  const int lk = l >> 4;

  const int wr = w >> 3;
  const int wq = w & 7;
  const int arow = row0 + wr * 16 + lr;
  short8 gh[2], gl[2];
  {
    const unsigned short* gH = g_hi + ((size_t)(b * NPOS + arow)) * FDIM + lk * 8;
    const unsigned short* gL = g_lo + ((size_t)(b * NPOS + arow)) * FDIM + lk * 8;
#pragma unroll
    for (int ks = 0; ks < 2; ++ks) {
      gh[ks] = *reinterpret_cast<const short8*>(gH + ks * 32);
      gl[ks] = *reinterpret_cast<const short8*>(gL + ks * 32);
    }
  }
  const unsigned short* fbh = f_hi + (size_t)b * NPOS * FDIM;
  const unsigned short* fbl = f_lo + (size_t)b * NPOS * FDIM;
  unsigned short* Pb = (unsigned short*)(beta + (size_t)b * NPOS * NPOS);
  unsigned short* prow = Pb + (size_t)arow * (2 * NPOS) + NPOS;
  const int rsw = lr & 7;
  float lsum = 0.f;
  const int srow_ = t >> 3, sch_ = t & 7;

#define STAGEA(buf, tile)                                                      \
  do {                                                                         \
    const int tr_ = (tile) * 128 + srow_;                                      \
    gload_lds16(fbh + (size_t)tr_ * FDIM + sch_ * 8,                           \
                (char*)&Fh[buf][0][0] + (size_t)t * 16);                       \
    gload_lds16(fbl + (size_t)tr_ * FDIM + sch_ * 8,                           \
                (char*)&Fl[buf][0][0] + (size_t)t * 16);                       \
  } while (0)

  STAGEA(0, 0);
  asm volatile("s_waitcnt vmcnt(0) lgkmcnt(0)\ns_barrier" ::: "memory");

  const int rrA = wq * 16 + lr;
  const int fsw = rrA & 7;
  int buf = 0;
  for (int tile = 0; tile < 32; ++tile) {
    if (tile < 31) STAGEA(buf ^ 1, tile + 1);
    __builtin_amdgcn_sched_barrier(0);
    const uint4 h0 = Fh[buf][rrA][lk ^ fsw];
    const uint4 h1 = Fh[buf][rrA][(lk + 4) ^ fsw];
    const uint4 q0 = Fl[buf][rrA][lk ^ fsw];
    const uint4 q1 = Fl[buf][rrA][(lk + 4) ^ fsw];
    f32x4 acca = {0.f, 0.f, 0.f, 0.f};
    f32x4 accb = {0.f, 0.f, 0.f, 0.f};
    acca = __builtin_amdgcn_mfma_f32_16x16x32_bf16(as_s8(h0), gh[0], acca, 0, 0, 0);
    accb = __builtin_amdgcn_mfma_f32_16x16x32_bf16(as_s8(h0), gl[0], accb, 0, 0, 0);
    acca = __builtin_amdgcn_mfma_f32_16x16x32_bf16(as_s8(q0), gh[0], acca, 0, 0, 0);
    accb = __builtin_amdgcn_mfma_f32_16x16x32_bf16(as_s8(h1), gh[1], accb, 0, 0, 0);
    acca = __builtin_amdgcn_mfma_f32_16x16x32_bf16(as_s8(q1), gh[1], acca, 0, 0, 0);
    accb = __builtin_amdgcn_mfma_f32_16x16x32_bf16(as_s8(h1), gl[1], accb, 0, 0, 0);
    const f32x4 acc = acca + accb;
    const int cq = tile * 128 + wq * 16 + lk * 4;
    const float e0 = __expf(acc[0]);
    const float e1 = __expf(acc[1]);
    const float e2 = __expf(acc[2]);
    const float e3 = __expf(acc[3]);
    lsum += (e0 + e1) + (e2 + e3);
    uint2 pk;
    pk.x = (unsigned)f2bf(e0) | ((unsigned)f2bf(e1) << 16);
    pk.y = (unsigned)f2bf(e2) | ((unsigned)f2bf(e3) << 16);
    const int sidx = (((cq >> 3) ^ rsw) << 3) | (cq & 7);
    *reinterpret_cast<uint2*>(prow + sidx) = pk;
    asm volatile("s_waitcnt vmcnt(1) lgkmcnt(0)\ns_barrier" ::: "memory");
    buf ^= 1;
  }
#undef STAGEA

  lsum += __shfl_xor(lsum, 16);
  lsum += __shfl_xor(lsum, 32);
  if (l < 16) partl[w][l] = lsum;
  __syncthreads();
  if (t < 32) {
    const int half = t >> 4;
    float s = 0.f;
#pragma unroll
    for (int q = 0; q < 8; ++q) s += partl[half * 8 + q][t & 15];
    linvs[t] = __frcp_rn(s);
  }
  asm volatile("s_waitcnt vmcnt(0) lgkmcnt(0)\ns_barrier" ::: "memory");

  const size_t hoff = (size_t)b * CDIM * NPOS;
  const unsigned short* Pub = (const unsigned short*)(beta + (size_t)b * NPOS * NPOS);

#define STAGEB(bufi, kt)                                                        \
  do {                                                                          \
    {                                                                           \
      const int slot_ = w * 128 + l;                                            \
      const unsigned short* g_ = h_t + hoff + (size_t)(slot_ >> 3) * NPOS +     \
                                 (size_t)((kt) * 8 + (slot_ & 7)) * 8;          \
      gload_lds16(g_, (unsigned short*)&Bb[bufi][0][0] + (size_t)(w * 128) * 8);\
    }                                                                           \
    {                                                                           \
      const int slot_ = w * 128 + 64 + l;                                       \
      const unsigned short* g_ = h_t + hoff + (size_t)(slot_ >> 3) * NPOS +     \
                                 (size_t)((kt) * 8 + (slot_ & 7)) * 8;          \
      gload_lds16(g_, (unsigned short*)&Bb[bufi][0][0] +                        \
                          (size_t)(w * 128 + 64) * 8);                          \
    }                                                                           \
    if (t < 256) {                                                              \
      const unsigned short* g_ = Pub + (size_t)(row0 + (t >> 3)) * (2 * NPOS) + \
                                 NPOS + (size_t)((kt) * 8 + (t & 7)) * 8;       \
      gload_lds16(g_, (unsigned short*)&Ab[bufi][0][0] + (size_t)(w * 64) * 8); \
    }                                                                           \
  } while (0)

  f32x4 acc0 = {0.f, 0.f, 0.f, 0.f}, acc1 = {0.f, 0.f, 0.f, 0.f};
  const int wrB = w & 1;
  const int wcB = w >> 1;
  const int arB = wrB * 16 + lr;
  const int c0 = wcB * 32 + lr;
  const int c1 = c0 + 16;
  const int brow = t >> 5;
  const int jj = t & 31;
  const float il_brow = linvs[brow];

  STAGEB(0, 0);
  asm volatile("s_waitcnt vmcnt(0) lgkmcnt(0)\ns_barrier" ::: "memory");

  buf = 0;
  for (int kt = 0; kt < 64; ++kt) {
    if (kt < 63) STAGEB(buf ^ 1, kt + 1);
    __builtin_amdgcn_sched_barrier(0);
    {
      const uint4 a0 = Ab[buf][arB][lk ^ (arB & 7)];
      const uint4 a1 = Ab[buf][arB][(4 + lk) ^ (arB & 7)];
      const uint4 b00 = Bb[buf][c0][lk ^ (c0 & 7)];
      const uint4 b01 = Bb[buf][c1][lk ^ (c1 & 7)];
      const uint4 b10 = Bb[buf][c0][(4 + lk) ^ (c0 & 7)];
      const uint4 b11 = Bb[buf][c1][(4 + lk) ^ (c1 & 7)];
      acc0 = __builtin_amdgcn_mfma_f32_16x16x32_bf16(as_s8(a0), as_s8(b00), acc0, 0, 0, 0);
      acc1 = __builtin_amdgcn_mfma_f32_16x16x32_bf16(as_s8(a0), as_s8(b01), acc1, 0, 0, 0);
      acc0 = __builtin_amdgcn_mfma_f32_16x16x32_bf16(as_s8(a1), as_s8(b10), acc0, 0, 0, 0);
      acc1 = __builtin_amdgcn_mfma_f32_16x16x32_bf16(as_s8(a1), as_s8(b11), acc1, 0, 0, 0);
    }
    {
      const unsigned* arow_ = reinterpret_cast<const unsigned*>(&Ab[buf][brow][0]);
      const unsigned u = arow_[(((jj >> 2) ^ (brow & 7)) << 2) | (jj & 3)];
      float2 v;
      v.x = bf2f((unsigned short)(u & 0xffffu)) * il_brow;
      v.y = bf2f((unsigned short)(u >> 16)) * il_brow;
      *reinterpret_cast<float2*>(beta + (size_t)(b * NPOS + row0 + brow) * NPOS +
                                 (size_t)kt * 64 + jj * 2) = v;
    }
    asm volatile("s_waitcnt vmcnt(1) lgkmcnt(0)\ns_barrier" ::: "memory");
    buf ^= 1;
  }
#undef STAGEB

  const float gam = gamma[0];
#pragma unroll
  for (int r = 0; r < 4; ++r) {
    const int lrr = wrB * 16 + lk * 4 + r;
    const int orow = row0 + lrr;
    const float sc = gam * linvs[lrr];
    const size_t i0 = ((size_t)b * NPOS + orow) * CDIM + wcB * 32 + lr;
    out[i0] = fmaf(sc, acc0[r], x[i0]);
    out[i0 + 16] = fmaf(sc, acc1[r], x[i0 + 16]);
  }
}

extern "C" void kernel_launch(void* const* d_in, const int* in_sizes, int n_in,
                              void* d_out, int out_size, void* d_ws, size_t ws_size,
                              hipStream_t stream) {
  (void)in_sizes; (void)n_in; (void)out_size;
  const float* x = (const float*)d_in[0];
  const float* Wf = (const float*)d_in[1];
  const float* Wg = (const float*)d_in[2];
  const float* Wh = (const float*)d_in[3];
  const float* gamma = (const float*)d_in[4];

  float* out = (float*)d_out;                                   // [2*4096*256]
  float* beta = out + (size_t)2 * NPOS * CDIM;                  // [2*4096*4096]

  unsigned short* h_t = (unsigned short*)d_ws;                  // [2*256*4096]
  unsigned short* f_hi = h_t + (size_t)2 * CDIM * NPOS;         // [8192*64] each
  unsigned short* f_lo = f_hi + (size_t)2 * NPOS * FDIM;
  unsigned short* g_hi = f_lo + (size_t)2 * NPOS * FDIM;
  unsigned short* g_lo = g_hi + (size_t)2 * NPOS * FDIM;
  float* lrow = (float*)(g_lo + (size_t)2 * NPOS * FDIM);       // [8192]
  unsigned short* Pws = (unsigned short*)(lrow + 2 * NPOS);     // [2*4096*4096] bf16

  const size_t need = ((char*)(Pws + (size_t)2 * NPOS * NPOS)) - (char*)d_ws;

  hipLaunchKernelGGL(proj_kernel, dim3(2 * NPOS / 16), dim3(256), 0, stream,
                     x, Wf, Wg, Wh, f_hi, f_lo, g_hi, g_lo, h_t, out);
  if (ws_size >= need) {
    hipLaunchKernelGGL(qk_l_kernel, dim3(256), dim3(1024), 0, stream,
                       f_hi, f_lo, g_hi, g_lo, Pws, lrow);
    hipLaunchKernelGGL(pv_split_kernel, dim3(256), dim3(1024), 0, stream,
                       h_t, Pws, lrow, gamma, beta, out);
  } else {
    hipLaunchKernelGGL(attn_fused_kernel, dim3(256), dim3(1024), 0, stream,
                       f_hi, f_lo, g_hi, g_lo, h_t, x, gamma, beta, out);
  }
}

// Round 19
// 125.840 us; speedup vs baseline: 1.0772x; 1.0772x over previous
//
#include <hip/hip_runtime.h>

#define NPOS 4096
#define CDIM 256
#define FDIM 64

typedef short short8 __attribute__((ext_vector_type(8)));
typedef float f32x4 __attribute__((ext_vector_type(4)));

__device__ __forceinline__ unsigned short f2bf(float v) {
  unsigned u = __float_as_uint(v);
  unsigned r = (u + 0x7fffu + ((u >> 16) & 1u)) >> 16;  // RNE
  return (unsigned short)r;
}
__device__ __forceinline__ float bf2f(unsigned short u) {
  return __uint_as_float((unsigned)u << 16);
}
__device__ __forceinline__ short8 as_s8(uint4 u) {
  return *reinterpret_cast<short8*>(&u);
}
__device__ __forceinline__ void gload_lds16(const void* g, void* l) {
  __builtin_amdgcn_global_load_lds(
      (const __attribute__((address_space(1))) unsigned int*)g,
      (__attribute__((address_space(3))) unsigned int*)l, 16, 0, 0);
}

// ---------------------------------------------------------------------------
// Kernel 1: projections + out = x init.
//   f planes pre-swizzled (chunk c of row r at c^(r&7)); g linear;
//   h_t = (x@Wh)^T bf16, pre-swizzled the same way.
// ---------------------------------------------------------------------------
__global__ __launch_bounds__(256) void proj_kernel(
    const float* __restrict__ x, const float* __restrict__ Wf,
    const float* __restrict__ Wg, const float* __restrict__ Wh,
    unsigned short* __restrict__ f_hi, unsigned short* __restrict__ f_lo,
    unsigned short* __restrict__ g_hi, unsigned short* __restrict__ g_lo,
    unsigned short* __restrict__ h_t, float* __restrict__ out) {
  __shared__ float xs[16][CDIM];
  const int row0 = blockIdx.x * 16;
  const int t = threadIdx.x;
  {
    const float4* xv = reinterpret_cast<const float4*>(x + (size_t)row0 * CDIM);
    float4* sv = reinterpret_cast<float4*>(&xs[0][0]);
    float4* ov = reinterpret_cast<float4*>(out + (size_t)row0 * CDIM);
#pragma unroll
    for (int i = 0; i < 4; ++i) {
      const float4 v = xv[t + 256 * i];
      sv[t + 256 * i] = v;
      ov[t + 256 * i] = v;   // out = x (PV partial sums atomically added later)
    }
  }
  __syncthreads();
  {
    float acc[16];
#pragma unroll
    for (int r = 0; r < 16; ++r) acc[r] = 0.f;
    for (int k = 0; k < CDIM; k += 4) {
      const float w0 = Wh[(size_t)(k + 0) * CDIM + t];
      const float w1 = Wh[(size_t)(k + 1) * CDIM + t];
      const float w2 = Wh[(size_t)(k + 2) * CDIM + t];
      const float w3 = Wh[(size_t)(k + 3) * CDIM + t];
#pragma unroll
      for (int r = 0; r < 16; ++r) {
        const float4 xv = *reinterpret_cast<const float4*>(&xs[r][k]);
        float a = acc[r];
        a = fmaf(xv.x, w0, a);
        a = fmaf(xv.y, w1, a);
        a = fmaf(xv.z, w2, a);
        a = fmaf(xv.w, w3, a);
        acc[r] = a;
      }
    }
    const int b = row0 >> 12;
    const int lr = row0 & (NPOS - 1);
    unsigned wd[8];
#pragma unroll
    for (int i = 0; i < 8; ++i)
      wd[i] = (unsigned)f2bf(acc[2 * i]) | ((unsigned)f2bf(acc[2 * i + 1]) << 16);
    uint4* base = reinterpret_cast<uint4*>(h_t + ((size_t)(b * CDIM + t)) * NPOS);
    const int m = t & 7;
    const int c0 = lr >> 3;   // even
    base[c0 ^ m] = make_uint4(wd[0], wd[1], wd[2], wd[3]);
    base[(c0 + 1) ^ m] = make_uint4(wd[4], wd[5], wd[6], wd[7]);
  }
  {
    const int col = t & 63;
    const int rb = (t >> 6) * 4;
    const int colq = col >> 3, cwi = col & 7;
    float af[4] = {0.f, 0.f, 0.f, 0.f};
    float ag[4] = {0.f, 0.f, 0.f, 0.f};
    for (int k = 0; k < CDIM; k += 4) {
      const float wf0 = Wf[(size_t)(k + 0) * FDIM + col];
      const float wf1 = Wf[(size_t)(k + 1) * FDIM + col];
      const float wf2 = Wf[(size_t)(k + 2) * FDIM + col];
      const float wf3 = Wf[(size_t)(k + 3) * FDIM + col];
      const float wg0 = Wg[(size_t)(k + 0) * FDIM + col];
      const float wg1 = Wg[(size_t)(k + 1) * FDIM + col];
      const float wg2 = Wg[(size_t)(k + 2) * FDIM + col];
      const float wg3 = Wg[(size_t)(k + 3) * FDIM + col];
#pragma unroll
      for (int r = 0; r < 4; ++r) {
        const float4 xv = *reinterpret_cast<const float4*>(&xs[rb + r][k]);
        float a = af[r], bb = ag[r];
        a = fmaf(xv.x, wf0, a); a = fmaf(xv.y, wf1, a);
        a = fmaf(xv.z, wf2, a); a = fmaf(xv.w, wf3, a);
        bb = fmaf(xv.x, wg0, bb); bb = fmaf(xv.y, wg1, bb);
        bb = fmaf(xv.z, wg2, bb); bb = fmaf(xv.w, wg3, bb);
        af[r] = a; ag[r] = bb;
      }
    }
#pragma unroll
    for (int r = 0; r < 4; ++r) {
      const int row = row0 + rb + r;
      const int ph = ((colq ^ (row & 7)) << 3) | cwi;
      const size_t of = (size_t)row * FDIM + ph;
      const size_t og = (size_t)row * FDIM + col;
      const unsigned short fh = f2bf(af[r]);
      const unsigned short gh = f2bf(ag[r]);
      f_hi[of] = fh;
      f_lo[of] = f2bf(af[r] - bf2f(fh));
      g_hi[og] = gh;
      g_lo[og] = f2bf(ag[r] - bf2f(gh));
    }
  }
}

// ---------------------------------------------------------------------------
// Kernel 2A: s = g f^T (bf16x3, swapped operands), P = bf16(exp(s)) -> Pws
// (swizzled 16B chunks by row&7), row sums -> lrow.
// 32-row blocks, 1024 threads / 16 waves, grid 256; 16 fat iterations over
// 256-col f tiles (r17 config — halved barrier count vs r16, -5.5 us).
// ---------------------------------------------------------------------------
__global__ __launch_bounds__(1024, 4) void qk_l_kernel(
    const unsigned short* __restrict__ f_hi, const unsigned short* __restrict__ f_lo,
    const unsigned short* __restrict__ g_hi, const unsigned short* __restrict__ g_lo,
    unsigned short* __restrict__ Pws, float* __restrict__ lrow) {
  __shared__ uint4 Fh[2][256][8];   // 64 KB
  __shared__ uint4 Fl[2][256][8];   // 64 KB
  __shared__ float partl[16][32];

  const int wg = blockIdx.x;
  const int wgid = (wg & 7) * 32 + (wg >> 3);   // bijective XCD chunking (256 wgs)
  const int b = wgid >> 7;
  const int row0 = (wgid & 127) * 32;
  const int t = threadIdx.x;
  const int w = t >> 6;     // 0..15: col strip w*16
  const int l = t & 63;
  const int lr = l & 15;
  const int lk = l >> 4;

  // g fragments (B operand) for BOTH row halves of the block
  short8 gh0[2], gl0[2], gh1[2], gl1[2];
  {
    const unsigned short* gH0 = g_hi + ((size_t)(b * NPOS + row0 + lr)) * FDIM + lk * 8;
    const unsigned short* gL0 = g_lo + ((size_t)(b * NPOS + row0 + lr)) * FDIM + lk * 8;
    const unsigned short* gH1 = gH0 + (size_t)16 * FDIM;
    const unsigned short* gL1 = gL0 + (size_t)16 * FDIM;
#pragma unroll
    for (int ks = 0; ks < 2; ++ks) {
      gh0[ks] = *reinterpret_cast<const short8*>(gH0 + ks * 32);
      gl0[ks] = *reinterpret_cast<const short8*>(gL0 + ks * 32);
      gh1[ks] = *reinterpret_cast<const short8*>(gH1 + ks * 32);
      gl1[ks] = *reinterpret_cast<const short8*>(gL1 + ks * 32);
    }
  }
  const unsigned short* fbh = f_hi + (size_t)b * NPOS * FDIM;
  const unsigned short* fbl = f_lo + (size_t)b * NPOS * FDIM;
  unsigned short* prow0 = Pws + (size_t)(b * NPOS + row0 + lr) * NPOS;
  unsigned short* prow1 = prow0 + (size_t)16 * NPOS;
  const int rsw = lr & 7;    // (16+lr)&7 == lr&7: same swizzle for both halves
  float lsum0 = 0.f, lsum1 = 0.f;

  // staging: 4 gloads/thread (2 per plane); slot = j*1024 + t covers 2048
#define STAGEA(buf, tile)                                                      \
  do {                                                                         \
    _Pragma("unroll")                                                          \
    for (int j = 0; j < 2; ++j) {                                              \
      const int slot_ = j * 1024 + t;                                          \
      const int row_ = slot_ >> 3, ch_ = slot_ & 7;                            \
      gload_lds16(fbh + (size_t)((tile) * 256 + row_) * FDIM + ch_ * 8,        \
                  (char*)&Fh[buf][0][0] + (size_t)slot_ * 16);                 \
      gload_lds16(fbl + (size_t)((tile) * 256 + row_) * FDIM + ch_ * 8,        \
                  (char*)&Fl[buf][0][0] + (size_t)slot_ * 16);                 \
    }                                                                          \
  } while (0)

  STAGEA(0, 0);
  asm volatile("s_waitcnt vmcnt(0) lgkmcnt(0)\ns_barrier" ::: "memory");

  const int rrA = w * 16 + lr;    // A row (f row) within 256-col tile
  const int fsw = rrA & 7;
  int buf = 0;
  for (int tile = 0; tile < 16; ++tile) {
    if (tile < 15) STAGEA(buf ^ 1, tile + 1);
    __builtin_amdgcn_sched_barrier(0);   // pin gloads at top (vmcnt count safety)
    const uint4 h0 = Fh[buf][rrA][lk ^ fsw];
    const uint4 h1 = Fh[buf][rrA][(lk + 4) ^ fsw];
    const uint4 q0 = Fl[buf][rrA][lk ^ fsw];
    const uint4 q1 = Fl[buf][rrA][(lk + 4) ^ fsw];
    // ---- row-half 0
    {
      f32x4 acca = {0.f, 0.f, 0.f, 0.f};
      f32x4 accb = {0.f, 0.f, 0.f, 0.f};
      acca = __builtin_amdgcn_mfma_f32_16x16x32_bf16(as_s8(h0), gh0[0], acca, 0, 0, 0);
      accb = __builtin_amdgcn_mfma_f32_16x16x32_bf16(as_s8(h0), gl0[0], accb, 0, 0, 0);
      acca = __builtin_amdgcn_mfma_f32_16x16x32_bf16(as_s8(q0), gh0[0], acca, 0, 0, 0);
      accb = __builtin_amdgcn_mfma_f32_16x16x32_bf16(as_s8(h1), gh0[1], accb, 0, 0, 0);
      acca = __builtin_amdgcn_mfma_f32_16x16x32_bf16(as_s8(q1), gh0[1], acca, 0, 0, 0);
      accb = __builtin_amdgcn_mfma_f32_16x16x32_bf16(as_s8(h1), gl0[1], accb, 0, 0, 0);
      const f32x4 acc = acca + accb;
      const int cq = tile * 256 + w * 16 + lk * 4;
      const float e0 = __expf(acc[0]);
      const float e1 = __expf(acc[1]);
      const float e2 = __expf(acc[2]);
      const float e3 = __expf(acc[3]);
      lsum0 += (e0 + e1) + (e2 + e3);
      uint2 pk;
      pk.x = (unsigned)f2bf(e0) | ((unsigned)f2bf(e1) << 16);
      pk.y = (unsigned)f2bf(e2) | ((unsigned)f2bf(e3) << 16);
      const int sidx = (((cq >> 3) ^ rsw) << 3) | (cq & 7);
      *reinterpret_cast<uint2*>(prow0 + sidx) = pk;
    }
    // ---- row-half 1
    {
      f32x4 acca = {0.f, 0.f, 0.f, 0.f};
      f32x4 accb = {0.f, 0.f, 0.f, 0.f};
      acca = __builtin_amdgcn_mfma_f32_16x16x32_bf16(as_s8(h0), gh1[0], acca, 0, 0, 0);
      accb = __builtin_amdgcn_mfma_f32_16x16x32_bf16(as_s8(h0), gl1[0], accb, 0, 0, 0);
      acca = __builtin_amdgcn_mfma_f32_16x16x32_bf16(as_s8(q0), gh1[0], acca, 0, 0, 0);
      accb = __builtin_amdgcn_mfma_f32_16x16x32_bf16(as_s8(h1), gh1[1], accb, 0, 0, 0);
      acca = __builtin_amdgcn_mfma_f32_16x16x32_bf16(as_s8(q1), gh1[1], acca, 0, 0, 0);
      accb = __builtin_amdgcn_mfma_f32_16x16x32_bf16(as_s8(h1), gl1[1], accb, 0, 0, 0);
      const f32x4 acc = acca + accb;
      const int cq = tile * 256 + w * 16 + lk * 4;
      const float e0 = __expf(acc[0]);
      const float e1 = __expf(acc[1]);
      const float e2 = __expf(acc[2]);
      const float e3 = __expf(acc[3]);
      lsum1 += (e0 + e1) + (e2 + e3);
      uint2 pk;
      pk.x = (unsigned)f2bf(e0) | ((unsigned)f2bf(e1) << 16);
      pk.y = (unsigned)f2bf(e2) | ((unsigned)f2bf(e3) << 16);
      const int sidx = (((cq >> 3) ^ rsw) << 3) | (cq & 7);
      *reinterpret_cast<uint2*>(prow1 + sidx) = pk;
    }
    // counted barrier: drain this iter's 4 gloads; own 2 P-stores in flight
    asm volatile("s_waitcnt vmcnt(2) lgkmcnt(0)\ns_barrier" ::: "memory");
    buf ^= 1;
  }
#undef STAGEA

  // row sums: lanes {l, l^16, l^32, l^48} share rows lr / 16+lr
  lsum0 += __shfl_xor(lsum0, 16);
  lsum0 += __shfl_xor(lsum0, 32);
  lsum1 += __shfl_xor(lsum1, 16);
  lsum1 += __shfl_xor(lsum1, 32);
  if (l < 16) {
    partl[w][l] = lsum0;
    partl[w][16 + l] = lsum1;
  }
  __syncthreads();
  if (t < 32) {
    float s = 0.f;
#pragma unroll
    for (int q = 0; q < 16; ++q) s += partl[q][t];
    lrow[(size_t)b * NPOS + row0 + t] = s;
  }
}

// ---------------------------------------------------------------------------
// Kernel 2B (r16/r17 config — measured best): beta = P/l (fp32, its K-half) +
// o_partial = beta @ h atomically added into out (pre-initialized to x).
// Block = 64 beta-rows x 256 cols x K-half(2048), 1024 threads / 16 waves.
// (r18's K-quarter fattening regressed: doubled atomics outweighed fewer
// barriers — reverted.)
// ---------------------------------------------------------------------------
__global__ __launch_bounds__(1024, 4) void pv_split_kernel(
    const unsigned short* __restrict__ h_t, const unsigned short* __restrict__ Pws,
    const float* __restrict__ lrow, const float* __restrict__ gamma,
    float* __restrict__ beta, float* __restrict__ out) {
  __shared__ uint4 Ab[2][64][8];     // P tile  [64 r][8 chunks]  8 KiB/buf
  __shared__ uint4 Bb[2][256][8];    // h tile  [256 c][8 chunks] 32 KiB/buf
  __shared__ float linvB[64];

  const int wg = blockIdx.x;
  const int wgid = (wg & 7) * 32 + (wg >> 3);   // bijective XCD chunking (256 wgs)
  const int b = wgid >> 7;
  const int khalf = (wgid >> 6) & 1;
  const int row0 = (wgid & 63) * 64;
  const int t = threadIdx.x;
  const int w = t >> 6;
  const int l = t & 63;
  const int lr = l & 15;
  const int lk = l >> 4;

  if (t < 64) linvB[t] = __frcp_rn(lrow[(size_t)b * NPOS + row0 + t]);

  const size_t hoff = (size_t)b * CDIM * NPOS;
  const unsigned short* Pb = Pws + (size_t)(b * NPOS + row0) * NPOS;
  const int kbase = khalf * 256;     // physical 16B-chunk base of this K-half

#define STAGEB(bufi, kt)                                                        \
  do {                                                                          \
    _Pragma("unroll")                                                           \
    for (int j = 0; j < 2; ++j) {                                               \
      const int slot_ = j * 1024 + t;                                           \
      const int col_ = slot_ >> 3, ch_ = slot_ & 7;                             \
      const unsigned short* g_ = h_t + hoff + (size_t)col_ * NPOS +             \
                                 (size_t)(kbase + (kt) * 8 + ch_) * 8;          \
      gload_lds16(g_, (char*)&Bb[bufi][0][0] + (size_t)slot_ * 16);             \
    }                                                                           \
    if (t < 512) {                                                              \
      const int row_ = t >> 3, ch_ = t & 7;                                     \
      const unsigned short* g_ = Pb + (size_t)row_ * NPOS +                     \
                                 (size_t)(kbase + (kt) * 8 + ch_) * 8;          \
      gload_lds16(g_, (char*)&Ab[bufi][0][0] + (size_t)t * 16);                 \
    }                                                                           \
  } while (0)

  f32x4 acc0 = {0.f, 0.f, 0.f, 0.f}, acc1 = {0.f, 0.f, 0.f, 0.f};
  f32x4 acc2 = {0.f, 0.f, 0.f, 0.f}, acc3 = {0.f, 0.f, 0.f, 0.f};
  const int wrB = w & 3;               // row quarter (0..3)
  const int wcB = w >> 2;              // col strip of 64 (0..3)
  const int arB = wrB * 16 + lr;       // local A row 0..63
  const int c0 = wcB * 64 + lr;
  const int c1 = c0 + 16;
  const int c2 = c0 + 32;
  const int c3 = c0 + 48;
  const int brow = t >> 4;             // beta-write row 0..63
  const int jj = t & 15;               // beta-write float4 index (cols jj*4..+3)

  STAGEB(0, 0);
  asm volatile("s_waitcnt vmcnt(0) lgkmcnt(0)\ns_barrier" ::: "memory");
  const float il_brow = linvB[brow];

  int buf = 0;
  for (int kt = 0; kt < 32; ++kt) {
    if (kt < 31) STAGEB(buf ^ 1, kt + 1);
    __builtin_amdgcn_sched_barrier(0);   // pin gloads at top (vmcnt count safety)
    // ---- MFMA: K=64 as 2 k-steps of 32, 4 col-tiles per wave
    {
      const uint4 a0 = Ab[buf][arB][lk ^ (arB & 7)];
      const uint4 a1 = Ab[buf][arB][(4 + lk) ^ (arB & 7)];
      const uint4 b00 = Bb[buf][c0][lk ^ (c0 & 7)];
      const uint4 b01 = Bb[buf][c1][lk ^ (c1 & 7)];
      const uint4 b02 = Bb[buf][c2][lk ^ (c2 & 7)];
      const uint4 b03 = Bb[buf][c3][lk ^ (c3 & 7)];
      acc0 = __builtin_amdgcn_mfma_f32_16x16x32_bf16(as_s8(a0), as_s8(b00), acc0, 0, 0, 0);
      acc1 = __builtin_amdgcn_mfma_f32_16x16x32_bf16(as_s8(a0), as_s8(b01), acc1, 0, 0, 0);
      acc2 = __builtin_amdgcn_mfma_f32_16x16x32_bf16(as_s8(a0), as_s8(b02), acc2, 0, 0, 0);
      acc3 = __builtin_amdgcn_mfma_f32_16x16x32_bf16(as_s8(a0), as_s8(b03), acc3, 0, 0, 0);
      const uint4 b10 = Bb[buf][c0][(4 + lk) ^ (c0 & 7)];
      const uint4 b11 = Bb[buf][c1][(4 + lk) ^ (c1 & 7)];
      const uint4 b12 = Bb[buf][c2][(4 + lk) ^ (c2 & 7)];
      const uint4 b13 = Bb[buf][c3][(4 + lk) ^ (c3 & 7)];
      acc0 = __builtin_amdgcn_mfma_f32_16x16x32_bf16(as_s8(a1), as_s8(b10), acc0, 0, 0, 0);
      acc1 = __builtin_amdgcn_mfma_f32_16x16x32_bf16(as_s8(a1), as_s8(b11), acc1, 0, 0, 0);
      acc2 = __builtin_amdgcn_mfma_f32_16x16x32_bf16(as_s8(a1), as_s8(b12), acc2, 0, 0, 0);
      acc3 = __builtin_amdgcn_mfma_f32_16x16x32_bf16(as_s8(a1), as_s8(b13), acc3, 0, 0, 0);
    }
    // ---- beta write: one float4/thread from staged A tile (swizzled read)
    {
      const uint4 u4 = Ab[buf][brow][(jj >> 1) ^ (brow & 7)];
      const uint2 u = (jj & 1) ? make_uint2(u4.z, u4.w) : make_uint2(u4.x, u4.y);
      float4 v;
      v.x = bf2f((unsigned short)(u.x & 0xffffu)) * il_brow;
      v.y = bf2f((unsigned short)(u.x >> 16)) * il_brow;
      v.z = bf2f((unsigned short)(u.y & 0xffffu)) * il_brow;
      v.w = bf2f((unsigned short)(u.y >> 16)) * il_brow;
      *reinterpret_cast<float4*>(beta + (size_t)(b * NPOS + row0 + brow) * NPOS +
                                 khalf * 2048 + kt * 64 + jj * 4) = v;
    }
    // counted barrier: newest outstanding = the beta store
    asm volatile("s_waitcnt vmcnt(1) lgkmcnt(0)\ns_barrier" ::: "memory");
    buf ^= 1;
  }
#undef STAGEB

  // epilogue: atomically add partial gamma*o/l into out (= x + both halves)
  const float gam = gamma[0];
#pragma unroll
  for (int r = 0; r < 4; ++r) {
    const int lrr = wrB * 16 + lk * 4 + r;
    const int orow = row0 + lrr;
    const float sc = gam * linvB[lrr];
    float* o = out + ((size_t)b * NPOS + orow) * CDIM + wcB * 64 + lr;
    atomicAdd(o, sc * acc0[r]);
    atomicAdd(o + 16, sc * acc1[r]);
    atomicAdd(o + 32, sc * acc2[r]);
    atomicAdd(o + 48, sc * acc3[r]);
  }
}

// ---------------------------------------------------------------------------
// FALLBACK (if ws too small for Pws): r14 fused kernel, P inside beta rows.
// ---------------------------------------------------------------------------
__global__ __launch_bounds__(1024, 4) void attn_fused_kernel(
    const unsigned short* __restrict__ f_hi, const unsigned short* __restrict__ f_lo,
    const unsigned short* __restrict__ g_hi, const unsigned short* __restrict__ g_lo,
    const unsigned short* __restrict__ h_t, const float* __restrict__ x,
    const float* __restrict__ gamma, float* __restrict__ beta,
    float* __restrict__ out) {
  __shared__ __align__(16) char shraw[110592];
  __shared__ float partl[16][16];
  __shared__ float linvs[32];
  uint4 (*Fh)[128][8] = reinterpret_cast<uint4(*)[128][8]>(shraw);
  uint4 (*Fl)[128][8] = reinterpret_cast<uint4(*)[128][8]>(shraw + 32768);
  uint4 (*Ab)[32][8] = reinterpret_cast<uint4(*)[32][8]>(shraw);
  uint4 (*Bb)[256][8] = reinterpret_cast<uint4(*)[256][8]>(shraw + 12288);

  const int wg = blockIdx.x;
  const int wgid = (wg & 7) * 32 + (wg >> 3);
  const int b = wgid >> 7;
  const int row0 = (wgid & 127) * 32;
  const int t = threadIdx.x;
  const int w = t >> 6;
  const int l = t & 63;
  const int lr = l & 15;
  const int lk = l >> 4;

  const int wr = w >> 3;
  const int wq = w & 7;
  const int arow = row0 + wr * 16 + lr;
  short8 gh[2], gl[2];
  {
    const unsigned short* gH = g_hi + ((size_t)(b * NPOS + arow)) * FDIM + lk * 8;
    const unsigned short* gL = g_lo + ((size_t)(b * NPOS + arow)) * FDIM + lk * 8;
#pragma unroll
    for (int ks = 0; ks < 2; ++ks) {
      gh[ks] = *reinterpret_cast<const short8*>(gH + ks * 32);
      gl[ks] = *reinterpret_cast<const short8*>(gL + ks * 32);
    }
  }
  const unsigned short* fbh = f_hi + (size_t)b * NPOS * FDIM;
  const unsigned short* fbl = f_lo + (size_t)b * NPOS * FDIM;
  unsigned short* Pb = (unsigned short*)(beta + (size_t)b * NPOS * NPOS);
  unsigned short* prow = Pb + (size_t)arow * (2 * NPOS) + NPOS;
  const int rsw = lr & 7;
  float lsum = 0.f;
  const int srow_ = t >> 3, sch_ = t & 7;

#define STAGEA(buf, tile)                                                      \
  do {                                                                         \
    const int tr_ = (tile) * 128 + srow_;                                      \
    gload_lds16(fbh + (size_t)tr_ * FDIM + sch_ * 8,                           \
                (char*)&Fh[buf][0][0] + (size_t)t * 16);                       \
    gload_lds16(fbl + (size_t)tr_ * FDIM + sch_ * 8,                           \
                (char*)&Fl[buf][0][0] + (size_t)t * 16);                       \
  } while (0)

  STAGEA(0, 0);
  asm volatile("s_waitcnt vmcnt(0) lgkmcnt(0)\ns_barrier" ::: "memory");

  const int rrA = wq * 16 + lr;
  const int fsw = rrA & 7;
  int buf = 0;
  for (int tile = 0; tile < 32; ++tile) {
    if (tile < 31) STAGEA(buf ^ 1, tile + 1);
    __builtin_amdgcn_sched_barrier(0);
    const uint4 h0 = Fh[buf][rrA][lk ^ fsw];
    const uint4 h1 = Fh[buf][rrA][(lk + 4) ^ fsw];
    const uint4 q0 = Fl[buf][rrA][lk ^ fsw];
    const uint4 q1 = Fl[buf][rrA][(lk + 4) ^ fsw];
    f32x4 acca = {0.f, 0.f, 0.f, 0.f};
    f32x4 accb = {0.f, 0.f, 0.f, 0.f};
    acca = __builtin_amdgcn_mfma_f32_16x16x32_bf16(as_s8(h0), gh[0], acca, 0, 0, 0);
    accb = __builtin_amdgcn_mfma_f32_16x16x32_bf16(as_s8(h0), gl[0], accb, 0, 0, 0);
    acca = __builtin_amdgcn_mfma_f32_16x16x32_bf16(as_s8(q0), gh[0], acca, 0, 0, 0);
    accb = __builtin_amdgcn_mfma_f32_16x16x32_bf16(as_s8(h1), gh[1], accb, 0, 0, 0);
    acca = __builtin_amdgcn_mfma_f32_16x16x32_bf16(as_s8(q1), gh[1], acca, 0, 0, 0);
    accb = __builtin_amdgcn_mfma_f32_16x16x32_bf16(as_s8(h1), gl[1], accb, 0, 0, 0);
    const f32x4 acc = acca + accb;
    const int cq = tile * 128 + wq * 16 + lk * 4;
    const float e0 = __expf(acc[0]);
    const float e1 = __expf(acc[1]);
    const float e2 = __expf(acc[2]);
    const float e3 = __expf(acc[3]);
    lsum += (e0 + e1) + (e2 + e3);
    uint2 pk;
    pk.x = (unsigned)f2bf(e0) | ((unsigned)f2bf(e1) << 16);
    pk.y = (unsigned)f2bf(e2) | ((unsigned)f2bf(e3) << 16);
    const int sidx = (((cq >> 3) ^ rsw) << 3) | (cq & 7);
    *reinterpret_cast<uint2*>(prow + sidx) = pk;
    asm volatile("s_waitcnt vmcnt(1) lgkmcnt(0)\ns_barrier" ::: "memory");
    buf ^= 1;
  }
#undef STAGEA

  lsum += __shfl_xor(lsum, 16);
  lsum += __shfl_xor(lsum, 32);
  if (l < 16) partl[w][l] = lsum;
  __syncthreads();
  if (t < 32) {
    const int half = t >> 4;
    float s = 0.f;
#pragma unroll
    for (int q = 0; q < 8; ++q) s += partl[half * 8 + q][t & 15];
    linvs[t] = __frcp_rn(s);
  }
  asm volatile("s_waitcnt vmcnt(0) lgkmcnt(0)\ns_barrier" ::: "memory");

  const size_t hoff = (size_t)b * CDIM * NPOS;
  const unsigned short* Pub = (const unsigned short*)(beta + (size_t)b * NPOS * NPOS);

#define STAGEB(bufi, kt)                                                        \
  do {                                                                          \
    {                                                                           \
      const int slot_ = w * 128 + l;                                            \
      const unsigned short* g_ = h_t + hoff + (size_t)(slot_ >> 3) * NPOS +     \
                                 (size_t)((kt) * 8 + (slot_ & 7)) * 8;          \
      gload_lds16(g_, (unsigned short*)&Bb[bufi][0][0] + (size_t)(w * 128) * 8);\
    }                                                                           \
    {                                                                           \
      const int slot_ = w * 128 + 64 + l;                                       \
      const unsigned short* g_ = h_t + hoff + (size_t)(slot_ >> 3) * NPOS +     \
                                 (size_t)((kt) * 8 + (slot_ & 7)) * 8;          \
      gload_lds16(g_, (unsigned short*)&Bb[bufi][0][0] +                        \
                          (size_t)(w * 128 + 64) * 8);                          \
    }                                                                           \
    if (t < 256) {                                                              \
      const unsigned short* g_ = Pub + (size_t)(row0 + (t >> 3)) * (2 * NPOS) + \
                                 NPOS + (size_t)((kt) * 8 + (t & 7)) * 8;       \
      gload_lds16(g_, (unsigned short*)&Ab[bufi][0][0] + (size_t)(w * 64) * 8); \
    }                                                                           \
  } while (0)

  f32x4 acc0 = {0.f, 0.f, 0.f, 0.f}, acc1 = {0.f, 0.f, 0.f, 0.f};
  const int wrB = w & 1;
  const int wcB = w >> 1;
  const int arB = wrB * 16 + lr;
  const int c0 = wcB * 32 + lr;
  const int c1 = c0 + 16;
  const int brow = t >> 5;
  const int jj = t & 31;
  const float il_brow = linvs[brow];

  STAGEB(0, 0);
  asm volatile("s_waitcnt vmcnt(0) lgkmcnt(0)\ns_barrier" ::: "memory");

  buf = 0;
  for (int kt = 0; kt < 64; ++kt) {
    if (kt < 63) STAGEB(buf ^ 1, kt + 1);
    __builtin_amdgcn_sched_barrier(0);
    {
      const uint4 a0 = Ab[buf][arB][lk ^ (arB & 7)];
      const uint4 a1 = Ab[buf][arB][(4 + lk) ^ (arB & 7)];
      const uint4 b00 = Bb[buf][c0][lk ^ (c0 & 7)];
      const uint4 b01 = Bb[buf][c1][lk ^ (c1 & 7)];
      const uint4 b10 = Bb[buf][c0][(4 + lk) ^ (c0 & 7)];
      const uint4 b11 = Bb[buf][c1][(4 + lk) ^ (c1 & 7)];
      acc0 = __builtin_amdgcn_mfma_f32_16x16x32_bf16(as_s8(a0), as_s8(b00), acc0, 0, 0, 0);
      acc1 = __builtin_amdgcn_mfma_f32_16x16x32_bf16(as_s8(a0), as_s8(b01), acc1, 0, 0, 0);
      acc0 = __builtin_amdgcn_mfma_f32_16x16x32_bf16(as_s8(a1), as_s8(b10), acc0, 0, 0, 0);
      acc1 = __builtin_amdgcn_mfma_f32_16x16x32_bf16(as_s8(a1), as_s8(b11), acc1, 0, 0, 0);
    }
    {
      const unsigned* arow_ = reinterpret_cast<const unsigned*>(&Ab[buf][brow][0]);
      const unsigned u = arow_[(((jj >> 2) ^ (brow & 7)) << 2) | (jj & 3)];
      float2 v;
      v.x = bf2f((unsigned short)(u & 0xffffu)) * il_brow;
      v.y = bf2f((unsigned short)(u >> 16)) * il_brow;
      *reinterpret_cast<float2*>(beta + (size_t)(b * NPOS + row0 + brow) * NPOS +
                                 (size_t)kt * 64 + jj * 2) = v;
    }
    asm volatile("s_waitcnt vmcnt(1) lgkmcnt(0)\ns_barrier" ::: "memory");
    buf ^= 1;
  }
#undef STAGEB

  const float gam = gamma[0];
#pragma unroll
  for (int r = 0; r < 4; ++r) {
    const int lrr = wrB * 16 + lk * 4 + r;
    const int orow = row0 + lrr;
    const float sc = gam * linvs[lrr];
    const size_t i0 = ((size_t)b * NPOS + orow) * CDIM + wcB * 32 + lr;
    out[i0] = fmaf(sc, acc0[r], x[i0]);
    out[i0 + 16] = fmaf(sc, acc1[r], x[i0 + 16]);
  }
}

extern "C" void kernel_launch(void* const* d_in, const int* in_sizes, int n_in,
                              void* d_out, int out_size, void* d_ws, size_t ws_size,
                              hipStream_t stream) {
  (void)in_sizes; (void)n_in; (void)out_size;
  const float* x = (const float*)d_in[0];
  const float* Wf = (const float*)d_in[1];
  const float* Wg = (const float*)d_in[2];
  const float* Wh = (const float*)d_in[3];
  const float* gamma = (const float*)d_in[4];

  float* out = (float*)d_out;                                   // [2*4096*256]
  float* beta = out + (size_t)2 * NPOS * CDIM;                  // [2*4096*4096]

  unsigned short* h_t = (unsigned short*)d_ws;                  // [2*256*4096]
  unsigned short* f_hi = h_t + (size_t)2 * CDIM * NPOS;         // [8192*64] each
  unsigned short* f_lo = f_hi + (size_t)2 * NPOS * FDIM;
  unsigned short* g_hi = f_lo + (size_t)2 * NPOS * FDIM;
  unsigned short* g_lo = g_hi + (size_t)2 * NPOS * FDIM;
  float* lrow = (float*)(g_lo + (size_t)2 * NPOS * FDIM);       // [8192]
  unsigned short* Pws = (unsigned short*)(lrow + 2 * NPOS);     // [2*4096*4096] bf16

  const size_t need = ((char*)(Pws + (size_t)2 * NPOS * NPOS)) - (char*)d_ws;

  hipLaunchKernelGGL(proj_kernel, dim3(2 * NPOS / 16), dim3(256), 0, stream,
                     x, Wf, Wg, Wh, f_hi, f_lo, g_hi, g_lo, h_t, out);
  if (ws_size >= need) {
    hipLaunchKernelGGL(qk_l_kernel, dim3(256), dim3(1024), 0, stream,
                       f_hi, f_lo, g_hi, g_lo, Pws, lrow);
    hipLaunchKernelGGL(pv_split_kernel, dim3(256), dim3(1024), 0, stream,
                       h_t, Pws, lrow, gamma, beta, out);
  } else {
    hipLaunchKernelGGL(attn_fused_kernel, dim3(256), dim3(1024), 0, stream,
                       f_hi, f_lo, g_hi, g_lo, h_t, x, gamma, beta, out);
  }
}

// Round 20
// 121.866 us; speedup vs baseline: 1.1123x; 1.0326x over previous
//
#include <hip/hip_runtime.h>

#define NPOS 4096
#define CDIM 256
#define FDIM 64

typedef short short8 __attribute__((ext_vector_type(8)));
typedef float f32x4 __attribute__((ext_vector_type(4)));

__device__ __forceinline__ unsigned short f2bf(float v) {
  unsigned u = __float_as_uint(v);
  unsigned r = (u + 0x7fffu + ((u >> 16) & 1u)) >> 16;  // RNE
  return (unsigned short)r;
}
__device__ __forceinline__ float bf2f(unsigned short u) {
  return __uint_as_float((unsigned)u << 16);
}
__device__ __forceinline__ short8 as_s8(uint4 u) {
  return *reinterpret_cast<short8*>(&u);
}
__device__ __forceinline__ void gload_lds16(const void* g, void* l) {
  __builtin_amdgcn_global_load_lds(
      (const __attribute__((address_space(1))) unsigned int*)g,
      (__attribute__((address_space(3))) unsigned int*)l, 16, 0, 0);
}

// ---------------------------------------------------------------------------
// Kernel 1: projections + out = x init (unchanged from r17).
// ---------------------------------------------------------------------------
__global__ __launch_bounds__(256) void proj_kernel(
    const float* __restrict__ x, const float* __restrict__ Wf,
    const float* __restrict__ Wg, const float* __restrict__ Wh,
    unsigned short* __restrict__ f_hi, unsigned short* __restrict__ f_lo,
    unsigned short* __restrict__ g_hi, unsigned short* __restrict__ g_lo,
    unsigned short* __restrict__ h_t, float* __restrict__ out) {
  __shared__ float xs[16][CDIM];
  const int row0 = blockIdx.x * 16;
  const int t = threadIdx.x;
  {
    const float4* xv = reinterpret_cast<const float4*>(x + (size_t)row0 * CDIM);
    float4* sv = reinterpret_cast<float4*>(&xs[0][0]);
    float4* ov = reinterpret_cast<float4*>(out + (size_t)row0 * CDIM);
#pragma unroll
    for (int i = 0; i < 4; ++i) {
      const float4 v = xv[t + 256 * i];
      sv[t + 256 * i] = v;
      ov[t + 256 * i] = v;   // out = x (used by the atomic fallback path)
    }
  }
  __syncthreads();
  {
    float acc[16];
#pragma unroll
    for (int r = 0; r < 16; ++r) acc[r] = 0.f;
    for (int k = 0; k < CDIM; k += 4) {
      const float w0 = Wh[(size_t)(k + 0) * CDIM + t];
      const float w1 = Wh[(size_t)(k + 1) * CDIM + t];
      const float w2 = Wh[(size_t)(k + 2) * CDIM + t];
      const float w3 = Wh[(size_t)(k + 3) * CDIM + t];
#pragma unroll
      for (int r = 0; r < 16; ++r) {
        const float4 xv = *reinterpret_cast<const float4*>(&xs[r][k]);
        float a = acc[r];
        a = fmaf(xv.x, w0, a);
        a = fmaf(xv.y, w1, a);
        a = fmaf(xv.z, w2, a);
        a = fmaf(xv.w, w3, a);
        acc[r] = a;
      }
    }
    const int b = row0 >> 12;
    const int lr = row0 & (NPOS - 1);
    unsigned wd[8];
#pragma unroll
    for (int i = 0; i < 8; ++i)
      wd[i] = (unsigned)f2bf(acc[2 * i]) | ((unsigned)f2bf(acc[2 * i + 1]) << 16);
    uint4* base = reinterpret_cast<uint4*>(h_t + ((size_t)(b * CDIM + t)) * NPOS);
    const int m = t & 7;
    const int c0 = lr >> 3;   // even
    base[c0 ^ m] = make_uint4(wd[0], wd[1], wd[2], wd[3]);
    base[(c0 + 1) ^ m] = make_uint4(wd[4], wd[5], wd[6], wd[7]);
  }
  {
    const int col = t & 63;
    const int rb = (t >> 6) * 4;
    const int colq = col >> 3, cwi = col & 7;
    float af[4] = {0.f, 0.f, 0.f, 0.f};
    float ag[4] = {0.f, 0.f, 0.f, 0.f};
    for (int k = 0; k < CDIM; k += 4) {
      const float wf0 = Wf[(size_t)(k + 0) * FDIM + col];
      const float wf1 = Wf[(size_t)(k + 1) * FDIM + col];
      const float wf2 = Wf[(size_t)(k + 2) * FDIM + col];
      const float wf3 = Wf[(size_t)(k + 3) * FDIM + col];
      const float wg0 = Wg[(size_t)(k + 0) * FDIM + col];
      const float wg1 = Wg[(size_t)(k + 1) * FDIM + col];
      const float wg2 = Wg[(size_t)(k + 2) * FDIM + col];
      const float wg3 = Wg[(size_t)(k + 3) * FDIM + col];
#pragma unroll
      for (int r = 0; r < 4; ++r) {
        const float4 xv = *reinterpret_cast<const float4*>(&xs[rb + r][k]);
        float a = af[r], bb = ag[r];
        a = fmaf(xv.x, wf0, a); a = fmaf(xv.y, wf1, a);
        a = fmaf(xv.z, wf2, a); a = fmaf(xv.w, wf3, a);
        bb = fmaf(xv.x, wg0, bb); bb = fmaf(xv.y, wg1, bb);
        bb = fmaf(xv.z, wg2, bb); bb = fmaf(xv.w, wg3, bb);
        af[r] = a; ag[r] = bb;
      }
    }
#pragma unroll
    for (int r = 0; r < 4; ++r) {
      const int row = row0 + rb + r;
      const int ph = ((colq ^ (row & 7)) << 3) | cwi;
      const size_t of = (size_t)row * FDIM + ph;
      const size_t og = (size_t)row * FDIM + col;
      const unsigned short fh = f2bf(af[r]);
      const unsigned short gh = f2bf(ag[r]);
      f_hi[of] = fh;
      f_lo[of] = f2bf(af[r] - bf2f(fh));
      g_hi[og] = gh;
      g_lo[og] = f2bf(ag[r] - bf2f(gh));
    }
  }
}

// ---------------------------------------------------------------------------
// Kernel 2A (unchanged from r17): s = g f^T, P = bf16(exp(s)) -> Pws,
// row sums -> lrow. 16 fat iterations over 256-col f tiles.
// ---------------------------------------------------------------------------
__global__ __launch_bounds__(1024, 4) void qk_l_kernel(
    const unsigned short* __restrict__ f_hi, const unsigned short* __restrict__ f_lo,
    const unsigned short* __restrict__ g_hi, const unsigned short* __restrict__ g_lo,
    unsigned short* __restrict__ Pws, float* __restrict__ lrow) {
  __shared__ uint4 Fh[2][256][8];   // 64 KB
  __shared__ uint4 Fl[2][256][8];   // 64 KB
  __shared__ float partl[16][32];

  const int wg = blockIdx.x;
  const int wgid = (wg & 7) * 32 + (wg >> 3);   // bijective XCD chunking (256 wgs)
  const int b = wgid >> 7;
  const int row0 = (wgid & 127) * 32;
  const int t = threadIdx.x;
  const int w = t >> 6;     // 0..15: col strip w*16
  const int l = t & 63;
  const int lr = l & 15;
  const int lk = l >> 4;

  short8 gh0[2], gl0[2], gh1[2], gl1[2];
  {
    const unsigned short* gH0 = g_hi + ((size_t)(b * NPOS + row0 + lr)) * FDIM + lk * 8;
    const unsigned short* gL0 = g_lo + ((size_t)(b * NPOS + row0 + lr)) * FDIM + lk * 8;
    const unsigned short* gH1 = gH0 + (size_t)16 * FDIM;
    const unsigned short* gL1 = gL0 + (size_t)16 * FDIM;
#pragma unroll
    for (int ks = 0; ks < 2; ++ks) {
      gh0[ks] = *reinterpret_cast<const short8*>(gH0 + ks * 32);
      gl0[ks] = *reinterpret_cast<const short8*>(gL0 + ks * 32);
      gh1[ks] = *reinterpret_cast<const short8*>(gH1 + ks * 32);
      gl1[ks] = *reinterpret_cast<const short8*>(gL1 + ks * 32);
    }
  }
  const unsigned short* fbh = f_hi + (size_t)b * NPOS * FDIM;
  const unsigned short* fbl = f_lo + (size_t)b * NPOS * FDIM;
  unsigned short* prow0 = Pws + (size_t)(b * NPOS + row0 + lr) * NPOS;
  unsigned short* prow1 = prow0 + (size_t)16 * NPOS;
  const int rsw = lr & 7;
  float lsum0 = 0.f, lsum1 = 0.f;

#define STAGEA(buf, tile)                                                      \
  do {                                                                         \
    _Pragma("unroll")                                                          \
    for (int j = 0; j < 2; ++j) {                                              \
      const int slot_ = j * 1024 + t;                                          \
      const int row_ = slot_ >> 3, ch_ = slot_ & 7;                            \
      gload_lds16(fbh + (size_t)((tile) * 256 + row_) * FDIM + ch_ * 8,        \
                  (char*)&Fh[buf][0][0] + (size_t)slot_ * 16);                 \
      gload_lds16(fbl + (size_t)((tile) * 256 + row_) * FDIM + ch_ * 8,        \
                  (char*)&Fl[buf][0][0] + (size_t)slot_ * 16);                 \
    }                                                                          \
  } while (0)

  STAGEA(0, 0);
  asm volatile("s_waitcnt vmcnt(0) lgkmcnt(0)\ns_barrier" ::: "memory");

  const int rrA = w * 16 + lr;
  const int fsw = rrA & 7;
  int buf = 0;
  for (int tile = 0; tile < 16; ++tile) {
    if (tile < 15) STAGEA(buf ^ 1, tile + 1);
    __builtin_amdgcn_sched_barrier(0);   // pin gloads at top (vmcnt count safety)
    const uint4 h0 = Fh[buf][rrA][lk ^ fsw];
    const uint4 h1 = Fh[buf][rrA][(lk + 4) ^ fsw];
    const uint4 q0 = Fl[buf][rrA][lk ^ fsw];
    const uint4 q1 = Fl[buf][rrA][(lk + 4) ^ fsw];
    // ---- row-half 0
    {
      f32x4 acca = {0.f, 0.f, 0.f, 0.f};
      f32x4 accb = {0.f, 0.f, 0.f, 0.f};
      acca = __builtin_amdgcn_mfma_f32_16x16x32_bf16(as_s8(h0), gh0[0], acca, 0, 0, 0);
      accb = __builtin_amdgcn_mfma_f32_16x16x32_bf16(as_s8(h0), gl0[0], accb, 0, 0, 0);
      acca = __builtin_amdgcn_mfma_f32_16x16x32_bf16(as_s8(q0), gh0[0], acca, 0, 0, 0);
      accb = __builtin_amdgcn_mfma_f32_16x16x32_bf16(as_s8(h1), gh0[1], accb, 0, 0, 0);
      acca = __builtin_amdgcn_mfma_f32_16x16x32_bf16(as_s8(q1), gh0[1], acca, 0, 0, 0);
      accb = __builtin_amdgcn_mfma_f32_16x16x32_bf16(as_s8(h1), gl0[1], accb, 0, 0, 0);
      const f32x4 acc = acca + accb;
      const int cq = tile * 256 + w * 16 + lk * 4;
      const float e0 = __expf(acc[0]);
      const float e1 = __expf(acc[1]);
      const float e2 = __expf(acc[2]);
      const float e3 = __expf(acc[3]);
      lsum0 += (e0 + e1) + (e2 + e3);
      uint2 pk;
      pk.x = (unsigned)f2bf(e0) | ((unsigned)f2bf(e1) << 16);
      pk.y = (unsigned)f2bf(e2) | ((unsigned)f2bf(e3) << 16);
      const int sidx = (((cq >> 3) ^ rsw) << 3) | (cq & 7);
      *reinterpret_cast<uint2*>(prow0 + sidx) = pk;
    }
    // ---- row-half 1
    {
      f32x4 acca = {0.f, 0.f, 0.f, 0.f};
      f32x4 accb = {0.f, 0.f, 0.f, 0.f};
      acca = __builtin_amdgcn_mfma_f32_16x16x32_bf16(as_s8(h0), gh1[0], acca, 0, 0, 0);
      accb = __builtin_amdgcn_mfma_f32_16x16x32_bf16(as_s8(h0), gl1[0], accb, 0, 0, 0);
      acca = __builtin_amdgcn_mfma_f32_16x16x32_bf16(as_s8(q0), gh1[0], acca, 0, 0, 0);
      accb = __builtin_amdgcn_mfma_f32_16x16x32_bf16(as_s8(h1), gh1[1], accb, 0, 0, 0);
      acca = __builtin_amdgcn_mfma_f32_16x16x32_bf16(as_s8(q1), gh1[1], acca, 0, 0, 0);
      accb = __builtin_amdgcn_mfma_f32_16x16x32_bf16(as_s8(h1), gl1[1], accb, 0, 0, 0);
      const f32x4 acc = acca + accb;
      const int cq = tile * 256 + w * 16 + lk * 4;
      const float e0 = __expf(acc[0]);
      const float e1 = __expf(acc[1]);
      const float e2 = __expf(acc[2]);
      const float e3 = __expf(acc[3]);
      lsum1 += (e0 + e1) + (e2 + e3);
      uint2 pk;
      pk.x = (unsigned)f2bf(e0) | ((unsigned)f2bf(e1) << 16);
      pk.y = (unsigned)f2bf(e2) | ((unsigned)f2bf(e3) << 16);
      const int sidx = (((cq >> 3) ^ rsw) << 3) | (cq & 7);
      *reinterpret_cast<uint2*>(prow1 + sidx) = pk;
    }
    asm volatile("s_waitcnt vmcnt(2) lgkmcnt(0)\ns_barrier" ::: "memory");
    buf ^= 1;
  }
#undef STAGEA

  lsum0 += __shfl_xor(lsum0, 16);
  lsum0 += __shfl_xor(lsum0, 32);
  lsum1 += __shfl_xor(lsum1, 16);
  lsum1 += __shfl_xor(lsum1, 32);
  if (l < 16) {
    partl[w][l] = lsum0;
    partl[w][16 + l] = lsum1;
  }
  __syncthreads();
  if (t < 32) {
    float s = 0.f;
#pragma unroll
    for (int q = 0; q < 16; ++q) s += partl[q][t];
    lrow[(size_t)b * NPOS + row0 + t] = s;
  }
}

// ---------------------------------------------------------------------------
// Kernel 2B: beta = P/l (fp32, its K-half) + o_partial = beta @ h (K-half).
// If opart != nullptr: plain stores of scaled partials to opart[khalf] plane
// (no atomics; reduce_out_kernel sums). Else: atomicAdd into out (r17 path).
// ---------------------------------------------------------------------------
__global__ __launch_bounds__(1024, 4) void pv_split_kernel(
    const unsigned short* __restrict__ h_t, const unsigned short* __restrict__ Pws,
    const float* __restrict__ lrow, const float* __restrict__ gamma,
    float* __restrict__ beta, float* __restrict__ out, float* __restrict__ opart) {
  __shared__ uint4 Ab[2][64][8];     // P tile  [64 r][8 chunks]  8 KiB/buf
  __shared__ uint4 Bb[2][256][8];    // h tile  [256 c][8 chunks] 32 KiB/buf
  __shared__ float linvB[64];

  const int wg = blockIdx.x;
  const int wgid = (wg & 7) * 32 + (wg >> 3);   // bijective XCD chunking (256 wgs)
  const int b = wgid >> 7;
  const int khalf = (wgid >> 6) & 1;
  const int row0 = (wgid & 63) * 64;
  const int t = threadIdx.x;
  const int w = t >> 6;
  const int l = t & 63;
  const int lr = l & 15;
  const int lk = l >> 4;

  if (t < 64) linvB[t] = __frcp_rn(lrow[(size_t)b * NPOS + row0 + t]);

  const size_t hoff = (size_t)b * CDIM * NPOS;
  const unsigned short* Pb = Pws + (size_t)(b * NPOS + row0) * NPOS;
  const int kbase = khalf * 256;     // physical 16B-chunk base of this K-half

#define STAGEB(bufi, kt)                                                        \
  do {                                                                          \
    _Pragma("unroll")                                                           \
    for (int j = 0; j < 2; ++j) {                                               \
      const int slot_ = j * 1024 + t;                                           \
      const int col_ = slot_ >> 3, ch_ = slot_ & 7;                             \
      const unsigned short* g_ = h_t + hoff + (size_t)col_ * NPOS +             \
                                 (size_t)(kbase + (kt) * 8 + ch_) * 8;          \
      gload_lds16(g_, (char*)&Bb[bufi][0][0] + (size_t)slot_ * 16);             \
    }                                                                           \
    if (t < 512) {                                                              \
      const int row_ = t >> 3, ch_ = t & 7;                                     \
      const unsigned short* g_ = Pb + (size_t)row_ * NPOS +                     \
                                 (size_t)(kbase + (kt) * 8 + ch_) * 8;          \
      gload_lds16(g_, (char*)&Ab[bufi][0][0] + (size_t)t * 16);                 \
    }                                                                           \
  } while (0)

  f32x4 acc0 = {0.f, 0.f, 0.f, 0.f}, acc1 = {0.f, 0.f, 0.f, 0.f};
  f32x4 acc2 = {0.f, 0.f, 0.f, 0.f}, acc3 = {0.f, 0.f, 0.f, 0.f};
  const int wrB = w & 3;               // row quarter (0..3)
  const int wcB = w >> 2;              // col strip of 64 (0..3)
  const int arB = wrB * 16 + lr;       // local A row 0..63
  const int c0 = wcB * 64 + lr;
  const int c1 = c0 + 16;
  const int c2 = c0 + 32;
  const int c3 = c0 + 48;
  const int brow = t >> 4;             // beta-write row 0..63
  const int jj = t & 15;               // beta-write float4 index (cols jj*4..+3)

  STAGEB(0, 0);
  asm volatile("s_waitcnt vmcnt(0) lgkmcnt(0)\ns_barrier" ::: "memory");
  const float il_brow = linvB[brow];

  int buf = 0;
  for (int kt = 0; kt < 32; ++kt) {
    if (kt < 31) STAGEB(buf ^ 1, kt + 1);
    __builtin_amdgcn_sched_barrier(0);   // pin gloads at top (vmcnt count safety)
    // ---- MFMA: K=64 as 2 k-steps of 32, 4 col-tiles per wave
    {
      const uint4 a0 = Ab[buf][arB][lk ^ (arB & 7)];
      const uint4 a1 = Ab[buf][arB][(4 + lk) ^ (arB & 7)];
      const uint4 b00 = Bb[buf][c0][lk ^ (c0 & 7)];
      const uint4 b01 = Bb[buf][c1][lk ^ (c1 & 7)];
      const uint4 b02 = Bb[buf][c2][lk ^ (c2 & 7)];
      const uint4 b03 = Bb[buf][c3][lk ^ (c3 & 7)];
      acc0 = __builtin_amdgcn_mfma_f32_16x16x32_bf16(as_s8(a0), as_s8(b00), acc0, 0, 0, 0);
      acc1 = __builtin_amdgcn_mfma_f32_16x16x32_bf16(as_s8(a0), as_s8(b01), acc1, 0, 0, 0);
      acc2 = __builtin_amdgcn_mfma_f32_16x16x32_bf16(as_s8(a0), as_s8(b02), acc2, 0, 0, 0);
      acc3 = __builtin_amdgcn_mfma_f32_16x16x32_bf16(as_s8(a0), as_s8(b03), acc3, 0, 0, 0);
      const uint4 b10 = Bb[buf][c0][(4 + lk) ^ (c0 & 7)];
      const uint4 b11 = Bb[buf][c1][(4 + lk) ^ (c1 & 7)];
      const uint4 b12 = Bb[buf][c2][(4 + lk) ^ (c2 & 7)];
      const uint4 b13 = Bb[buf][c3][(4 + lk) ^ (c3 & 7)];
      acc0 = __builtin_amdgcn_mfma_f32_16x16x32_bf16(as_s8(a1), as_s8(b10), acc0, 0, 0, 0);
      acc1 = __builtin_amdgcn_mfma_f32_16x16x32_bf16(as_s8(a1), as_s8(b11), acc1, 0, 0, 0);
      acc2 = __builtin_amdgcn_mfma_f32_16x16x32_bf16(as_s8(a1), as_s8(b12), acc2, 0, 0, 0);
      acc3 = __builtin_amdgcn_mfma_f32_16x16x32_bf16(as_s8(a1), as_s8(b13), acc3, 0, 0, 0);
    }
    // ---- beta write: one float4/thread from staged A tile (swizzled read)
    {
      const uint4 u4 = Ab[buf][brow][(jj >> 1) ^ (brow & 7)];
      const uint2 u = (jj & 1) ? make_uint2(u4.z, u4.w) : make_uint2(u4.x, u4.y);
      float4 v;
      v.x = bf2f((unsigned short)(u.x & 0xffffu)) * il_brow;
      v.y = bf2f((unsigned short)(u.x >> 16)) * il_brow;
      v.z = bf2f((unsigned short)(u.y & 0xffffu)) * il_brow;
      v.w = bf2f((unsigned short)(u.y >> 16)) * il_brow;
      *reinterpret_cast<float4*>(beta + (size_t)(b * NPOS + row0 + brow) * NPOS +
                                 khalf * 2048 + kt * 64 + jj * 4) = v;
    }
    // counted barrier: newest outstanding = the beta store
    asm volatile("s_waitcnt vmcnt(1) lgkmcnt(0)\ns_barrier" ::: "memory");
    buf ^= 1;
  }
#undef STAGEB

  // epilogue: scaled partials -> opart plane (plain stores) or atomics to out
  const float gam = gamma[0];
  if (opart) {
    float* op = opart + (size_t)khalf * 2 * NPOS * CDIM;
#pragma unroll
    for (int r = 0; r < 4; ++r) {
      const int lrr = wrB * 16 + lk * 4 + r;
      const int orow = row0 + lrr;
      const float sc = gam * linvB[lrr];
      float* o = op + ((size_t)b * NPOS + orow) * CDIM + wcB * 64 + lr;
      o[0] = sc * acc0[r];
      o[16] = sc * acc1[r];
      o[32] = sc * acc2[r];
      o[48] = sc * acc3[r];
    }
  } else {
#pragma unroll
    for (int r = 0; r < 4; ++r) {
      const int lrr = wrB * 16 + lk * 4 + r;
      const int orow = row0 + lrr;
      const float sc = gam * linvB[lrr];
      float* o = out + ((size_t)b * NPOS + orow) * CDIM + wcB * 64 + lr;
      atomicAdd(o, sc * acc0[r]);
      atomicAdd(o + 16, sc * acc1[r]);
      atomicAdd(o + 32, sc * acc2[r]);
      atomicAdd(o + 48, sc * acc3[r]);
    }
  }
}

// ---------------------------------------------------------------------------
// Kernel 3 (only on the no-atomic path): out = x + p0 + p1.
// ---------------------------------------------------------------------------
__global__ __launch_bounds__(256) void reduce_out_kernel(
    const float* __restrict__ x, const float* __restrict__ opart,
    float* __restrict__ out) {
  const size_t i = ((size_t)blockIdx.x * 256 + threadIdx.x) * 4;
  const float4 xv = *reinterpret_cast<const float4*>(x + i);
  const float4 a = *reinterpret_cast<const float4*>(opart + i);
  const float4 bq = *reinterpret_cast<const float4*>(opart + (size_t)2 * NPOS * CDIM + i);
  float4 r;
  r.x = xv.x + a.x + bq.x;
  r.y = xv.y + a.y + bq.y;
  r.z = xv.z + a.z + bq.z;
  r.w = xv.w + a.w + bq.w;
  *reinterpret_cast<float4*>(out + i) = r;
}

// ---------------------------------------------------------------------------
// FALLBACK (if ws too small for Pws): r14 fused kernel, P inside beta rows.
// ---------------------------------------------------------------------------
__global__ __launch_bounds__(1024, 4) void attn_fused_kernel(
    const unsigned short* __restrict__ f_hi, const unsigned short* __restrict__ f_lo,
    const unsigned short* __restrict__ g_hi, const unsigned short* __restrict__ g_lo,
    const unsigned short* __restrict__ h_t, const float* __restrict__ x,
    const float* __restrict__ gamma, float* __restrict__ beta,
    float* __restrict__ out) {
  __shared__ __align__(16) char shraw[110592];
  __shared__ float partl[16][16];
  __shared__ float linvs[32];
  uint4 (*Fh)[128][8] = reinterpret_cast<uint4(*)[128][8]>(shraw);
  uint4 (*Fl)[128][8] = reinterpret_cast<uint4(*)[128][8]>(shraw + 32768);
  uint4 (*Ab)[32][8] = reinterpret_cast<uint4(*)[32][8]>(shraw);
  uint4 (*Bb)[256][8] = reinterpret_cast<uint4(*)[256][8]>(shraw + 12288);

  const int wg = blockIdx.x;
  const int wgid = (wg & 7) * 32 + (wg >> 3);
  const int b = wgid >> 7;
  const int row0 = (wgid & 127) * 32;
  const int t = threadIdx.x;
  const int w = t >> 6;
  const int l = t & 63;
  const int lr = l & 15;
  const int lk = l >> 4;

  const int wr = w >> 3;
  const int wq = w & 7;
  const int arow = row0 + wr * 16 + lr;
  short8 gh[2], gl[2];
  {
    const unsigned short* gH = g_hi + ((size_t)(b * NPOS + arow)) * FDIM + lk * 8;
    const unsigned short* gL = g_lo + ((size_t)(b * NPOS + arow)) * FDIM + lk * 8;
#pragma unroll
    for (int ks = 0; ks < 2; ++ks) {
      gh[ks] = *reinterpret_cast<const short8*>(gH + ks * 32);
      gl[ks] = *reinterpret_cast<const short8*>(gL + ks * 32);
    }
  }
  const unsigned short* fbh = f_hi + (size_t)b * NPOS * FDIM;
  const unsigned short* fbl = f_lo + (size_t)b * NPOS * FDIM;
  unsigned short* Pb = (unsigned short*)(beta + (size_t)b * NPOS * NPOS);
  unsigned short* prow = Pb + (size_t)arow * (2 * NPOS) + NPOS;
  const int rsw = lr & 7;
  float lsum = 0.f;
  const int srow_ = t >> 3, sch_ = t & 7;

#define STAGEA(buf, tile)                                                      \
  do {                                                                         \
    const int tr_ = (tile) * 128 + srow_;                                      \
    gload_lds16(fbh + (size_t)tr_ * FDIM + sch_ * 8,                           \
                (char*)&Fh[buf][0][0] + (size_t)t * 16);                       \
    gload_lds16(fbl + (size_t)tr_ * FDIM + sch_ * 8,                           \
                (char*)&Fl[buf][0][0] + (size_t)t * 16);                       \
  } while (0)

  STAGEA(0, 0);
  asm volatile("s_waitcnt vmcnt(0) lgkmcnt(0)\ns_barrier" ::: "memory");

  const int rrA = wq * 16 + lr;
  const int fsw = rrA & 7;
  int buf = 0;
  for (int tile = 0; tile < 32; ++tile) {
    if (tile < 31) STAGEA(buf ^ 1, tile + 1);
    __builtin_amdgcn_sched_barrier(0);
    const uint4 h0 = Fh[buf][rrA][lk ^ fsw];
    const uint4 h1 = Fh[buf][rrA][(lk + 4) ^ fsw];
    const uint4 q0 = Fl[buf][rrA][lk ^ fsw];
    const uint4 q1 = Fl[buf][rrA][(lk + 4) ^ fsw];
    f32x4 acca = {0.f, 0.f, 0.f, 0.f};
    f32x4 accb = {0.f, 0.f, 0.f, 0.f};
    acca = __builtin_amdgcn_mfma_f32_16x16x32_bf16(as_s8(h0), gh[0], acca, 0, 0, 0);
    accb = __builtin_amdgcn_mfma_f32_16x16x32_bf16(as_s8(h0), gl[0], accb, 0, 0, 0);
    acca = __builtin_amdgcn_mfma_f32_16x16x32_bf16(as_s8(q0), gh[0], acca, 0, 0, 0);
    accb = __builtin_amdgcn_mfma_f32_16x16x32_bf16(as_s8(h1), gh[1], accb, 0, 0, 0);
    acca = __builtin_amdgcn_mfma_f32_16x16x32_bf16(as_s8(q1), gh[1], acca, 0, 0, 0);
    accb = __builtin_amdgcn_mfma_f32_16x16x32_bf16(as_s8(h1), gl[1], accb, 0, 0, 0);
    const f32x4 acc = acca + accb;
    const int cq = tile * 128 + wq * 16 + lk * 4;
    const float e0 = __expf(acc[0]);
    const float e1 = __expf(acc[1]);
    const float e2 = __expf(acc[2]);
    const float e3 = __expf(acc[3]);
    lsum += (e0 + e1) + (e2 + e3);
    uint2 pk;
    pk.x = (unsigned)f2bf(e0) | ((unsigned)f2bf(e1) << 16);
    pk.y = (unsigned)f2bf(e2) | ((unsigned)f2bf(e3) << 16);
    const int sidx = (((cq >> 3) ^ rsw) << 3) | (cq & 7);
    *reinterpret_cast<uint2*>(prow + sidx) = pk;
    asm volatile("s_waitcnt vmcnt(1) lgkmcnt(0)\ns_barrier" ::: "memory");
    buf ^= 1;
  }
#undef STAGEA

  lsum += __shfl_xor(lsum, 16);
  lsum += __shfl_xor(lsum, 32);
  if (l < 16) partl[w][l] = lsum;
  __syncthreads();
  if (t < 32) {
    const int half = t >> 4;
    float s = 0.f;
#pragma unroll
    for (int q = 0; q < 8; ++q) s += partl[half * 8 + q][t & 15];
    linvs[t] = __frcp_rn(s);
  }
  asm volatile("s_waitcnt vmcnt(0) lgkmcnt(0)\ns_barrier" ::: "memory");

  const size_t hoff = (size_t)b * CDIM * NPOS;
  const unsigned short* Pub = (const unsigned short*)(beta + (size_t)b * NPOS * NPOS);

#define STAGEB(bufi, kt)                                                        \
  do {                                                                          \
    {                                                                           \
      const int slot_ = w * 128 + l;                                            \
      const unsigned short* g_ = h_t + hoff + (size_t)(slot_ >> 3) * NPOS +     \
                                 (size_t)((kt) * 8 + (slot_ & 7)) * 8;          \
      gload_lds16(g_, (unsigned short*)&Bb[bufi][0][0] + (size_t)(w * 128) * 8);\
    }                                                                           \
    {                                                                           \
      const int slot_ = w * 128 + 64 + l;                                       \
      const unsigned short* g_ = h_t + hoff + (size_t)(slot_ >> 3) * NPOS +     \
                                 (size_t)((kt) * 8 + (slot_ & 7)) * 8;          \
      gload_lds16(g_, (unsigned short*)&Bb[bufi][0][0] +                        \
                          (size_t)(w * 128 + 64) * 8);                          \
    }                                                                           \
    if (t < 256) {                                                              \
      const unsigned short* g_ = Pub + (size_t)(row0 + (t >> 3)) * (2 * NPOS) + \
                                 NPOS + (size_t)((kt) * 8 + (t & 7)) * 8;       \
      gload_lds16(g_, (unsigned short*)&Ab[bufi][0][0] + (size_t)(w * 64) * 8); \
    }                                                                           \
  } while (0)

  f32x4 acc0 = {0.f, 0.f, 0.f, 0.f}, acc1 = {0.f, 0.f, 0.f, 0.f};
  const int wrB = w & 1;
  const int wcB = w >> 1;
  const int arB = wrB * 16 + lr;
  const int c0 = wcB * 32 + lr;
  const int c1 = c0 + 16;
  const int brow = t >> 5;
  const int jj = t & 31;
  const float il_brow = linvs[brow];

  STAGEB(0, 0);
  asm volatile("s_waitcnt vmcnt(0) lgkmcnt(0)\ns_barrier" ::: "memory");

  buf = 0;
  for (int kt = 0; kt < 64; ++kt) {
    if (kt < 63) STAGEB(buf ^ 1, kt + 1);
    __builtin_amdgcn_sched_barrier(0);
    {
      const uint4 a0 = Ab[buf][arB][lk ^ (arB & 7)];
      const uint4 a1 = Ab[buf][arB][(4 + lk) ^ (arB & 7)];
      const uint4 b00 = Bb[buf][c0][lk ^ (c0 & 7)];
      const uint4 b01 = Bb[buf][c1][lk ^ (c1 & 7)];
      const uint4 b10 = Bb[buf][c0][(4 + lk) ^ (c0 & 7)];
      const uint4 b11 = Bb[buf][c1][(4 + lk) ^ (c1 & 7)];
      acc0 = __builtin_amdgcn_mfma_f32_16x16x32_bf16(as_s8(a0), as_s8(b00), acc0, 0, 0, 0);
      acc1 = __builtin_amdgcn_mfma_f32_16x16x32_bf16(as_s8(a0), as_s8(b01), acc1, 0, 0, 0);
      acc0 = __builtin_amdgcn_mfma_f32_16x16x32_bf16(as_s8(a1), as_s8(b10), acc0, 0, 0, 0);
      acc1 = __builtin_amdgcn_mfma_f32_16x16x32_bf16(as_s8(a1), as_s8(b11), acc1, 0, 0, 0);
    }
    {
      const unsigned* arow_ = reinterpret_cast<const unsigned*>(&Ab[buf][brow][0]);
      const unsigned u = arow_[(((jj >> 2) ^ (brow & 7)) << 2) | (jj & 3)];
      float2 v;
      v.x = bf2f((unsigned short)(u & 0xffffu)) * il_brow;
      v.y = bf2f((unsigned short)(u >> 16)) * il_brow;
      *reinterpret_cast<float2*>(beta + (size_t)(b * NPOS + row0 + brow) * NPOS +
                                 (size_t)kt * 64 + jj * 2) = v;
    }
    asm volatile("s_waitcnt vmcnt(1) lgkmcnt(0)\ns_barrier" ::: "memory");
    buf ^= 1;
  }
#undef STAGEB

  const float gam = gamma[0];
#pragma unroll
  for (int r = 0; r < 4; ++r) {
    const int lrr = wrB * 16 + lk * 4 + r;
    const int orow = row0 + lrr;
    const float sc = gam * linvs[lrr];
    const size_t i0 = ((size_t)b * NPOS + orow) * CDIM + wcB * 32 + lr;
    out[i0] = fmaf(sc, acc0[r], x[i0]);
    out[i0 + 16] = fmaf(sc, acc1[r], x[i0 + 16]);
  }
}

extern "C" void kernel_launch(void* const* d_in, const int* in_sizes, int n_in,
                              void* d_out, int out_size, void* d_ws, size_t ws_size,
                              hipStream_t stream) {
  (void)in_sizes; (void)n_in; (void)out_size;
  const float* x = (const float*)d_in[0];
  const float* Wf = (const float*)d_in[1];
  const float* Wg = (const float*)d_in[2];
  const float* Wh = (const float*)d_in[3];
  const float* gamma = (const float*)d_in[4];

  float* out = (float*)d_out;                                   // [2*4096*256]
  float* beta = out + (size_t)2 * NPOS * CDIM;                  // [2*4096*4096]

  unsigned short* h_t = (unsigned short*)d_ws;                  // [2*256*4096]
  unsigned short* f_hi = h_t + (size_t)2 * CDIM * NPOS;         // [8192*64] each
  unsigned short* f_lo = f_hi + (size_t)2 * NPOS * FDIM;
  unsigned short* g_hi = f_lo + (size_t)2 * NPOS * FDIM;
  unsigned short* g_lo = g_hi + (size_t)2 * NPOS * FDIM;
  float* lrow = (float*)(g_lo + (size_t)2 * NPOS * FDIM);       // [8192]
  unsigned short* Pws = (unsigned short*)(lrow + 2 * NPOS);     // [2*4096*4096] bf16
  float* opart = (float*)(Pws + (size_t)2 * NPOS * NPOS);       // [2][2*4096*256]

  const size_t need = ((char*)opart) - (char*)d_ws;
  const size_t need2 = ((char*)(opart + (size_t)4 * NPOS * CDIM)) - (char*)d_ws;

  hipLaunchKernelGGL(proj_kernel, dim3(2 * NPOS / 16), dim3(256), 0, stream,
                     x, Wf, Wg, Wh, f_hi, f_lo, g_hi, g_lo, h_t, out);
  if (ws_size >= need2) {
    // no-atomic path: partial planes + reduce
    hipLaunchKernelGGL(qk_l_kernel, dim3(256), dim3(1024), 0, stream,
                       f_hi, f_lo, g_hi, g_lo, Pws, lrow);
    hipLaunchKernelGGL(pv_split_kernel, dim3(256), dim3(1024), 0, stream,
                       h_t, Pws, lrow, gamma, beta, out, opart);
    hipLaunchKernelGGL(reduce_out_kernel, dim3(2 * NPOS * CDIM / 1024), dim3(256),
                       0, stream, x, opart, out);
  } else if (ws_size >= need) {
    // r17 path (atomics)
    hipLaunchKernelGGL(qk_l_kernel, dim3(256), dim3(1024), 0, stream,
                       f_hi, f_lo, g_hi, g_lo, Pws, lrow);
    hipLaunchKernelGGL(pv_split_kernel, dim3(256), dim3(1024), 0, stream,
                       h_t, Pws, lrow, gamma, beta, out, nullptr);
  } else {
    hipLaunchKernelGGL(attn_fused_kernel, dim3(256), dim3(1024), 0, stream,
                       f_hi, f_lo, g_hi, g_lo, h_t, x, gamma, beta, out);
  }
}

// Round 21
// 112.379 us; speedup vs baseline: 1.2062x; 1.0844x over previous
//
#include <hip/hip_runtime.h>

#define NPOS 4096
#define CDIM 256
#define FDIM 64

typedef short short8 __attribute__((ext_vector_type(8)));
typedef float f32x4 __attribute__((ext_vector_type(4)));

__device__ __forceinline__ unsigned short f2bf(float v) {
  unsigned u = __float_as_uint(v);
  unsigned r = (u + 0x7fffu + ((u >> 16) & 1u)) >> 16;  // RNE
  return (unsigned short)r;
}
__device__ __forceinline__ float bf2f(unsigned short u) {
  return __uint_as_float((unsigned)u << 16);
}
__device__ __forceinline__ short8 as_s8(uint4 u) {
  return *reinterpret_cast<short8*>(&u);
}
__device__ __forceinline__ void gload_lds16(const void* g, void* l) {
  __builtin_amdgcn_global_load_lds(
      (const __attribute__((address_space(1))) unsigned int*)g,
      (__attribute__((address_space(3))) unsigned int*)l, 16, 0, 0);
}

// ---------------------------------------------------------------------------
// Kernel 0: split concatenated weights into W^T bf16 hi/lo planes [384][256].
// cols 0..63 = Wf, 64..127 = Wg, 128..383 = Wh.
// ---------------------------------------------------------------------------
__global__ __launch_bounds__(256) void wsplit_kernel(
    const float* __restrict__ Wf, const float* __restrict__ Wg,
    const float* __restrict__ Wh, unsigned short* __restrict__ WThi,
    unsigned short* __restrict__ WTlo) {
  const int cw = blockIdx.x;   // 0..383
  const int k = threadIdx.x;   // 0..255
  float v;
  if (cw < 64) v = Wf[(size_t)k * 64 + cw];
  else if (cw < 128) v = Wg[(size_t)k * 64 + (cw - 64)];
  else v = Wh[(size_t)k * 256 + (cw - 128)];
  const unsigned short hi = f2bf(v);
  WThi[(size_t)cw * 256 + k] = hi;
  WTlo[(size_t)cw * 256 + k] = f2bf(v - bf2f(hi));
}

// ---------------------------------------------------------------------------
// Kernel 1 (MFMA proj): block = 32 x-rows, 1024 threads / 16 waves.
// x tile split to hi/lo bf16 in swizzled LDS; 48 16x16 output tiles:
//   h (unswapped, A=x, B=Wh^T): lane -> 4 consecutive h_t k's (uint2 store,
//     h_t pre-swizzle chunk^(col&7) as before);
//   f/g (swapped, A=W^T, B=x): lane -> 4 consecutive weight cols (uint2 into
//     f swizzled / g linear planes, exactly what qk_l consumes).
// All bf16x3. One barrier total; weights read from L2 (384 KB, hot).
// ---------------------------------------------------------------------------
__global__ __launch_bounds__(1024, 4) void proj_mfma_kernel(
    const float* __restrict__ x, const unsigned short* __restrict__ WThi,
    const unsigned short* __restrict__ WTlo,
    unsigned short* __restrict__ f_hi, unsigned short* __restrict__ f_lo,
    unsigned short* __restrict__ g_hi, unsigned short* __restrict__ g_lo,
    unsigned short* __restrict__ h_t) {
  __shared__ uint4 Xh[32][32];   // x hi bf16: [row][16B chunk], chunk^(row&7)
  __shared__ uint4 Xl[32][32];   // x lo
  const int grow0 = blockIdx.x * 32;   // global x row base (0..8191)
  const int bidx = grow0 >> 12;        // batch
  const int t = threadIdx.x;
  const int w = t >> 6;
  const int l = t & 63;
  const int lr = l & 15;
  const int lk = l >> 4;

  // ---- stage x tile, split hi/lo
  {
    const int srow = t >> 5;
    const int k0 = (t & 31) * 8;
    const float* xp = x + (size_t)(grow0 + srow) * CDIM + k0;
    const float4 v0 = *reinterpret_cast<const float4*>(xp);
    const float4 v1 = *reinterpret_cast<const float4*>(xp + 4);
    const unsigned short h0 = f2bf(v0.x), h1 = f2bf(v0.y), h2 = f2bf(v0.z),
                         h3 = f2bf(v0.w), h4 = f2bf(v1.x), h5 = f2bf(v1.y),
                         h6 = f2bf(v1.z), h7 = f2bf(v1.w);
    uint4 ph, pl;
    ph.x = (unsigned)h0 | ((unsigned)h1 << 16);
    ph.y = (unsigned)h2 | ((unsigned)h3 << 16);
    ph.z = (unsigned)h4 | ((unsigned)h5 << 16);
    ph.w = (unsigned)h6 | ((unsigned)h7 << 16);
    pl.x = (unsigned)f2bf(v0.x - bf2f(h0)) | ((unsigned)f2bf(v0.y - bf2f(h1)) << 16);
    pl.y = (unsigned)f2bf(v0.z - bf2f(h2)) | ((unsigned)f2bf(v0.w - bf2f(h3)) << 16);
    pl.z = (unsigned)f2bf(v1.x - bf2f(h4)) | ((unsigned)f2bf(v1.y - bf2f(h5)) << 16);
    pl.w = (unsigned)f2bf(v1.z - bf2f(h6)) | ((unsigned)f2bf(v1.w - bf2f(h7)) << 16);
    const int ch = (t & 31) ^ (srow & 7);
    Xh[srow][ch] = ph;
    Xl[srow][ch] = pl;
  }
  __syncthreads();

  // ---- 3 tiles per wave
#pragma unroll
  for (int i = 0; i < 3; ++i) {
    const int tau = w * 3 + i;
    if (tau < 32) {
      // ---------- h tile: A = x rows, B = Wh cols ----------
      const int mt = tau >> 4;     // row half
      const int nt = tau & 15;     // col tile
      const int arow = mt * 16 + lr;
      const int asw = arow & 7;
      const int cw = 128 + nt * 16 + lr;   // WT col
      const unsigned short* bh = WThi + (size_t)cw * 256 + lk * 8;
      const unsigned short* bl = WTlo + (size_t)cw * 256 + lk * 8;
      f32x4 acc = {0.f, 0.f, 0.f, 0.f};
#pragma unroll
      for (int ks = 0; ks < 8; ++ks) {
        const int o = (ks * 4 + lk) ^ asw;
        const uint4 ah = Xh[arow][o];
        const uint4 al = Xl[arow][o];
        const uint4 bhv = *reinterpret_cast<const uint4*>(bh + ks * 32);
        const uint4 blv = *reinterpret_cast<const uint4*>(bl + ks * 32);
        acc = __builtin_amdgcn_mfma_f32_16x16x32_bf16(as_s8(ah), as_s8(bhv), acc, 0, 0, 0);
        acc = __builtin_amdgcn_mfma_f32_16x16x32_bf16(as_s8(al), as_s8(bhv), acc, 0, 0, 0);
        acc = __builtin_amdgcn_mfma_f32_16x16x32_bf16(as_s8(ah), as_s8(blv), acc, 0, 0, 0);
      }
      const int col = nt * 16 + lr;                 // h column 0..255
      const int k0 = (grow0 & 4095) + mt * 16 + lk * 4;   // k position
      const int phys = (((k0 >> 3) ^ (col & 7)) << 3) | (k0 & 7);
      uint2 pk;
      pk.x = (unsigned)f2bf(acc[0]) | ((unsigned)f2bf(acc[1]) << 16);
      pk.y = (unsigned)f2bf(acc[2]) | ((unsigned)f2bf(acc[3]) << 16);
      *reinterpret_cast<uint2*>(h_t + ((size_t)(bidx * CDIM + col)) * NPOS + phys) = pk;
    } else {
      // ---------- f/g tile: A = W cols (swapped), B = x rows ----------
      const int tp = tau - 32;
      const int mt = tp >> 1;      // weight col tile 0..7 (0-3 f, 4-7 g)
      const int nt = tp & 1;       // row half
      const int cw = mt * 16 + lr;          // WT col 0..127 (A row)
      const unsigned short* ahp = WThi + (size_t)cw * 256 + lk * 8;
      const unsigned short* alp = WTlo + (size_t)cw * 256 + lk * 8;
      const int xrow = nt * 16 + lr;
      const int xsw = xrow & 7;
      f32x4 acc = {0.f, 0.f, 0.f, 0.f};
#pragma unroll
      for (int ks = 0; ks < 8; ++ks) {
        const int o = (ks * 4 + lk) ^ xsw;
        const uint4 ah = *reinterpret_cast<const uint4*>(ahp + ks * 32);
        const uint4 al = *reinterpret_cast<const uint4*>(alp + ks * 32);
        const uint4 bh = Xh[xrow][o];
        const uint4 bl = Xl[xrow][o];
        acc = __builtin_amdgcn_mfma_f32_16x16x32_bf16(as_s8(ah), as_s8(bh), acc, 0, 0, 0);
        acc = __builtin_amdgcn_mfma_f32_16x16x32_bf16(as_s8(al), as_s8(bh), acc, 0, 0, 0);
        acc = __builtin_amdgcn_mfma_f32_16x16x32_bf16(as_s8(ah), as_s8(bl), acc, 0, 0, 0);
      }
      // lane: x-row = nt*16 + lr ; weight cols wc0..wc0+3
      const int xn = nt * 16 + lr;
      const int grow = grow0 + xn;          // global row for f/g planes
      const int wc0 = mt * 16 + lk * 4;
      const unsigned short e0 = f2bf(acc[0]);
      const unsigned short e1 = f2bf(acc[1]);
      const unsigned short e2 = f2bf(acc[2]);
      const unsigned short e3 = f2bf(acc[3]);
      uint2 pkh, pkl;
      pkh.x = (unsigned)e0 | ((unsigned)e1 << 16);
      pkh.y = (unsigned)e2 | ((unsigned)e3 << 16);
      pkl.x = (unsigned)f2bf(acc[0] - bf2f(e0)) |
              ((unsigned)f2bf(acc[1] - bf2f(e1)) << 16);
      pkl.y = (unsigned)f2bf(acc[2] - bf2f(e2)) |
              ((unsigned)f2bf(acc[3] - bf2f(e3)) << 16);
      if (wc0 < 64) {           // f plane: swizzled chunks by row&7
        const int cc = wc0;
        const int phys = (((cc >> 3) ^ (grow & 7)) << 3) | (cc & 7);
        *reinterpret_cast<uint2*>(f_hi + (size_t)grow * FDIM + phys) = pkh;
        *reinterpret_cast<uint2*>(f_lo + (size_t)grow * FDIM + phys) = pkl;
      } else {                  // g plane: linear
        const int cc = wc0 - 64;
        *reinterpret_cast<uint2*>(g_hi + (size_t)grow * FDIM + cc) = pkh;
        *reinterpret_cast<uint2*>(g_lo + (size_t)grow * FDIM + cc) = pkl;
      }
    }
  }
}

// ---------------------------------------------------------------------------
// OLD scalar proj (fallback path only).
// ---------------------------------------------------------------------------
__global__ __launch_bounds__(256) void proj_kernel(
    const float* __restrict__ x, const float* __restrict__ Wf,
    const float* __restrict__ Wg, const float* __restrict__ Wh,
    unsigned short* __restrict__ f_hi, unsigned short* __restrict__ f_lo,
    unsigned short* __restrict__ g_hi, unsigned short* __restrict__ g_lo,
    unsigned short* __restrict__ h_t, float* __restrict__ out) {
  __shared__ float xs[16][CDIM];
  const int row0 = blockIdx.x * 16;
  const int t = threadIdx.x;
  {
    const float4* xv = reinterpret_cast<const float4*>(x + (size_t)row0 * CDIM);
    float4* sv = reinterpret_cast<float4*>(&xs[0][0]);
    float4* ov = reinterpret_cast<float4*>(out + (size_t)row0 * CDIM);
#pragma unroll
    for (int i = 0; i < 4; ++i) {
      const float4 v = xv[t + 256 * i];
      sv[t + 256 * i] = v;
      ov[t + 256 * i] = v;
    }
  }
  __syncthreads();
  {
    float acc[16];
#pragma unroll
    for (int r = 0; r < 16; ++r) acc[r] = 0.f;
    for (int k = 0; k < CDIM; k += 4) {
      const float w0 = Wh[(size_t)(k + 0) * CDIM + t];
      const float w1 = Wh[(size_t)(k + 1) * CDIM + t];
      const float w2 = Wh[(size_t)(k + 2) * CDIM + t];
      const float w3 = Wh[(size_t)(k + 3) * CDIM + t];
#pragma unroll
      for (int r = 0; r < 16; ++r) {
        const float4 xv = *reinterpret_cast<const float4*>(&xs[r][k]);
        float a = acc[r];
        a = fmaf(xv.x, w0, a);
        a = fmaf(xv.y, w1, a);
        a = fmaf(xv.z, w2, a);
        a = fmaf(xv.w, w3, a);
        acc[r] = a;
      }
    }
    const int b = row0 >> 12;
    const int lr = row0 & (NPOS - 1);
    unsigned wd[8];
#pragma unroll
    for (int i = 0; i < 8; ++i)
      wd[i] = (unsigned)f2bf(acc[2 * i]) | ((unsigned)f2bf(acc[2 * i + 1]) << 16);
    uint4* base = reinterpret_cast<uint4*>(h_t + ((size_t)(b * CDIM + t)) * NPOS);
    const int m = t & 7;
    const int c0 = lr >> 3;
    base[c0 ^ m] = make_uint4(wd[0], wd[1], wd[2], wd[3]);
    base[(c0 + 1) ^ m] = make_uint4(wd[4], wd[5], wd[6], wd[7]);
  }
  {
    const int col = t & 63;
    const int rb = (t >> 6) * 4;
    const int colq = col >> 3, cwi = col & 7;
    float af[4] = {0.f, 0.f, 0.f, 0.f};
    float ag[4] = {0.f, 0.f, 0.f, 0.f};
    for (int k = 0; k < CDIM; k += 4) {
      const float wf0 = Wf[(size_t)(k + 0) * FDIM + col];
      const float wf1 = Wf[(size_t)(k + 1) * FDIM + col];
      const float wf2 = Wf[(size_t)(k + 2) * FDIM + col];
      const float wf3 = Wf[(size_t)(k + 3) * FDIM + col];
      const float wg0 = Wg[(size_t)(k + 0) * FDIM + col];
      const float wg1 = Wg[(size_t)(k + 1) * FDIM + col];
      const float wg2 = Wg[(size_t)(k + 2) * FDIM + col];
      const float wg3 = Wg[(size_t)(k + 3) * FDIM + col];
#pragma unroll
      for (int r = 0; r < 4; ++r) {
        const float4 xv = *reinterpret_cast<const float4*>(&xs[rb + r][k]);
        float a = af[r], bb = ag[r];
        a = fmaf(xv.x, wf0, a); a = fmaf(xv.y, wf1, a);
        a = fmaf(xv.z, wf2, a); a = fmaf(xv.w, wf3, a);
        bb = fmaf(xv.x, wg0, bb); bb = fmaf(xv.y, wg1, bb);
        bb = fmaf(xv.z, wg2, bb); bb = fmaf(xv.w, wg3, bb);
        af[r] = a; ag[r] = bb;
      }
    }
#pragma unroll
    for (int r = 0; r < 4; ++r) {
      const int row = row0 + rb + r;
      const int ph = ((colq ^ (row & 7)) << 3) | cwi;
      const size_t of = (size_t)row * FDIM + ph;
      const size_t og = (size_t)row * FDIM + col;
      const unsigned short fh = f2bf(af[r]);
      const unsigned short gh = f2bf(ag[r]);
      f_hi[of] = fh;
      f_lo[of] = f2bf(af[r] - bf2f(fh));
      g_hi[og] = gh;
      g_lo[og] = f2bf(ag[r] - bf2f(gh));
    }
  }
}

// ---------------------------------------------------------------------------
// Kernel 2A (unchanged from r17): s = g f^T, P = bf16(exp(s)) -> Pws,
// row sums -> lrow. 16 fat iterations over 256-col f tiles.
// ---------------------------------------------------------------------------
__global__ __launch_bounds__(1024, 4) void qk_l_kernel(
    const unsigned short* __restrict__ f_hi, const unsigned short* __restrict__ f_lo,
    const unsigned short* __restrict__ g_hi, const unsigned short* __restrict__ g_lo,
    unsigned short* __restrict__ Pws, float* __restrict__ lrow) {
  __shared__ uint4 Fh[2][256][8];   // 64 KB
  __shared__ uint4 Fl[2][256][8];   // 64 KB
  __shared__ float partl[16][32];

  const int wg = blockIdx.x;
  const int wgid = (wg & 7) * 32 + (wg >> 3);   // bijective XCD chunking (256 wgs)
  const int b = wgid >> 7;
  const int row0 = (wgid & 127) * 32;
  const int t = threadIdx.x;
  const int w = t >> 6;     // 0..15: col strip w*16
  const int l = t & 63;
  const int lr = l & 15;
  const int lk = l >> 4;

  short8 gh0[2], gl0[2], gh1[2], gl1[2];
  {
    const unsigned short* gH0 = g_hi + ((size_t)(b * NPOS + row0 + lr)) * FDIM + lk * 8;
    const unsigned short* gL0 = g_lo + ((size_t)(b * NPOS + row0 + lr)) * FDIM + lk * 8;
    const unsigned short* gH1 = gH0 + (size_t)16 * FDIM;
    const unsigned short* gL1 = gL0 + (size_t)16 * FDIM;
#pragma unroll
    for (int ks = 0; ks < 2; ++ks) {
      gh0[ks] = *reinterpret_cast<const short8*>(gH0 + ks * 32);
      gl0[ks] = *reinterpret_cast<const short8*>(gL0 + ks * 32);
      gh1[ks] = *reinterpret_cast<const short8*>(gH1 + ks * 32);
      gl1[ks] = *reinterpret_cast<const short8*>(gL1 + ks * 32);
    }
  }
  const unsigned short* fbh = f_hi + (size_t)b * NPOS * FDIM;
  const unsigned short* fbl = f_lo + (size_t)b * NPOS * FDIM;
  unsigned short* prow0 = Pws + (size_t)(b * NPOS + row0 + lr) * NPOS;
  unsigned short* prow1 = prow0 + (size_t)16 * NPOS;
  const int rsw = lr & 7;
  float lsum0 = 0.f, lsum1 = 0.f;

#define STAGEA(buf, tile)                                                      \
  do {                                                                         \
    _Pragma("unroll")                                                          \
    for (int j = 0; j < 2; ++j) {                                              \
      const int slot_ = j * 1024 + t;                                          \
      const int row_ = slot_ >> 3, ch_ = slot_ & 7;                            \
      gload_lds16(fbh + (size_t)((tile) * 256 + row_) * FDIM + ch_ * 8,        \
                  (char*)&Fh[buf][0][0] + (size_t)slot_ * 16);                 \
      gload_lds16(fbl + (size_t)((tile) * 256 + row_) * FDIM + ch_ * 8,        \
                  (char*)&Fl[buf][0][0] + (size_t)slot_ * 16);                 \
    }                                                                          \
  } while (0)

  STAGEA(0, 0);
  asm volatile("s_waitcnt vmcnt(0) lgkmcnt(0)\ns_barrier" ::: "memory");

  const int rrA = w * 16 + lr;
  const int fsw = rrA & 7;
  int buf = 0;
  for (int tile = 0; tile < 16; ++tile) {
    if (tile < 15) STAGEA(buf ^ 1, tile + 1);
    __builtin_amdgcn_sched_barrier(0);
    const uint4 h0 = Fh[buf][rrA][lk ^ fsw];
    const uint4 h1 = Fh[buf][rrA][(lk + 4) ^ fsw];
    const uint4 q0 = Fl[buf][rrA][lk ^ fsw];
    const uint4 q1 = Fl[buf][rrA][(lk + 4) ^ fsw];
    {
      f32x4 acca = {0.f, 0.f, 0.f, 0.f};
      f32x4 accb = {0.f, 0.f, 0.f, 0.f};
      acca = __builtin_amdgcn_mfma_f32_16x16x32_bf16(as_s8(h0), gh0[0], acca, 0, 0, 0);
      accb = __builtin_amdgcn_mfma_f32_16x16x32_bf16(as_s8(h0), gl0[0], accb, 0, 0, 0);
      acca = __builtin_amdgcn_mfma_f32_16x16x32_bf16(as_s8(q0), gh0[0], acca, 0, 0, 0);
      accb = __builtin_amdgcn_mfma_f32_16x16x32_bf16(as_s8(h1), gh0[1], accb, 0, 0, 0);
      acca = __builtin_amdgcn_mfma_f32_16x16x32_bf16(as_s8(q1), gh0[1], acca, 0, 0, 0);
      accb = __builtin_amdgcn_mfma_f32_16x16x32_bf16(as_s8(h1), gl0[1], accb, 0, 0, 0);
      const f32x4 acc = acca + accb;
      const int cq = tile * 256 + w * 16 + lk * 4;
      const float e0 = __expf(acc[0]);
      const float e1 = __expf(acc[1]);
      const float e2 = __expf(acc[2]);
      const float e3 = __expf(acc[3]);
      lsum0 += (e0 + e1) + (e2 + e3);
      uint2 pk;
      pk.x = (unsigned)f2bf(e0) | ((unsigned)f2bf(e1) << 16);
      pk.y = (unsigned)f2bf(e2) | ((unsigned)f2bf(e3) << 16);
      const int sidx = (((cq >> 3) ^ rsw) << 3) | (cq & 7);
      *reinterpret_cast<uint2*>(prow0 + sidx) = pk;
    }
    {
      f32x4 acca = {0.f, 0.f, 0.f, 0.f};
      f32x4 accb = {0.f, 0.f, 0.f, 0.f};
      acca = __builtin_amdgcn_mfma_f32_16x16x32_bf16(as_s8(h0), gh1[0], acca, 0, 0, 0);
      accb = __builtin_amdgcn_mfma_f32_16x16x32_bf16(as_s8(h0), gl1[0], accb, 0, 0, 0);
      acca = __builtin_amdgcn_mfma_f32_16x16x32_bf16(as_s8(q0), gh1[0], acca, 0, 0, 0);
      accb = __builtin_amdgcn_mfma_f32_16x16x32_bf16(as_s8(h1), gh1[1], accb, 0, 0, 0);
      acca = __builtin_amdgcn_mfma_f32_16x16x32_bf16(as_s8(q1), gh1[1], acca, 0, 0, 0);
      accb = __builtin_amdgcn_mfma_f32_16x16x32_bf16(as_s8(h1), gl1[1], accb, 0, 0, 0);
      const f32x4 acc = acca + accb;
      const int cq = tile * 256 + w * 16 + lk * 4;
      const float e0 = __expf(acc[0]);
      const float e1 = __expf(acc[1]);
      const float e2 = __expf(acc[2]);
      const float e3 = __expf(acc[3]);
      lsum1 += (e0 + e1) + (e2 + e3);
      uint2 pk;
      pk.x = (unsigned)f2bf(e0) | ((unsigned)f2bf(e1) << 16);
      pk.y = (unsigned)f2bf(e2) | ((unsigned)f2bf(e3) << 16);
      const int sidx = (((cq >> 3) ^ rsw) << 3) | (cq & 7);
      *reinterpret_cast<uint2*>(prow1 + sidx) = pk;
    }
    asm volatile("s_waitcnt vmcnt(2) lgkmcnt(0)\ns_barrier" ::: "memory");
    buf ^= 1;
  }
#undef STAGEA

  lsum0 += __shfl_xor(lsum0, 16);
  lsum0 += __shfl_xor(lsum0, 32);
  lsum1 += __shfl_xor(lsum1, 16);
  lsum1 += __shfl_xor(lsum1, 32);
  if (l < 16) {
    partl[w][l] = lsum0;
    partl[w][16 + l] = lsum1;
  }
  __syncthreads();
  if (t < 32) {
    float s = 0.f;
#pragma unroll
    for (int q = 0; q < 16; ++q) s += partl[q][t];
    lrow[(size_t)b * NPOS + row0 + t] = s;
  }
}

// ---------------------------------------------------------------------------
// Kernel 2B (unchanged from r20): beta = P/l + o_partial = beta @ h.
// opart != nullptr: plain stores to partial planes; else atomics.
// ---------------------------------------------------------------------------
__global__ __launch_bounds__(1024, 4) void pv_split_kernel(
    const unsigned short* __restrict__ h_t, const unsigned short* __restrict__ Pws,
    const float* __restrict__ lrow, const float* __restrict__ gamma,
    float* __restrict__ beta, float* __restrict__ out, float* __restrict__ opart) {
  __shared__ uint4 Ab[2][64][8];
  __shared__ uint4 Bb[2][256][8];
  __shared__ float linvB[64];

  const int wg = blockIdx.x;
  const int wgid = (wg & 7) * 32 + (wg >> 3);
  const int b = wgid >> 7;
  const int khalf = (wgid >> 6) & 1;
  const int row0 = (wgid & 63) * 64;
  const int t = threadIdx.x;
  const int w = t >> 6;
  const int l = t & 63;
  const int lr = l & 15;
  const int lk = l >> 4;

  if (t < 64) linvB[t] = __frcp_rn(lrow[(size_t)b * NPOS + row0 + t]);

  const size_t hoff = (size_t)b * CDIM * NPOS;
  const unsigned short* Pb = Pws + (size_t)(b * NPOS + row0) * NPOS;
  const int kbase = khalf * 256;

#define STAGEB(bufi, kt)                                                        \
  do {                                                                          \
    _Pragma("unroll")                                                           \
    for (int j = 0; j < 2; ++j) {                                               \
      const int slot_ = j * 1024 + t;                                           \
      const int col_ = slot_ >> 3, ch_ = slot_ & 7;                             \
      const unsigned short* g_ = h_t + hoff + (size_t)col_ * NPOS +             \
                                 (size_t)(kbase + (kt) * 8 + ch_) * 8;          \
      gload_lds16(g_, (char*)&Bb[bufi][0][0] + (size_t)slot_ * 16);             \
    }                                                                           \
    if (t < 512) {                                                              \
      const int row_ = t >> 3, ch_ = t & 7;                                     \
      const unsigned short* g_ = Pb + (size_t)row_ * NPOS +                     \
                                 (size_t)(kbase + (kt) * 8 + ch_) * 8;          \
      gload_lds16(g_, (char*)&Ab[bufi][0][0] + (size_t)t * 16);                 \
    }                                                                           \
  } while (0)

  f32x4 acc0 = {0.f, 0.f, 0.f, 0.f}, acc1 = {0.f, 0.f, 0.f, 0.f};
  f32x4 acc2 = {0.f, 0.f, 0.f, 0.f}, acc3 = {0.f, 0.f, 0.f, 0.f};
  const int wrB = w & 3;
  const int wcB = w >> 2;
  const int arB = wrB * 16 + lr;
  const int c0 = wcB * 64 + lr;
  const int c1 = c0 + 16;
  const int c2 = c0 + 32;
  const int c3 = c0 + 48;
  const int brow = t >> 4;
  const int jj = t & 15;

  STAGEB(0, 0);
  asm volatile("s_waitcnt vmcnt(0) lgkmcnt(0)\ns_barrier" ::: "memory");
  const float il_brow = linvB[brow];

  int buf = 0;
  for (int kt = 0; kt < 32; ++kt) {
    if (kt < 31) STAGEB(buf ^ 1, kt + 1);
    __builtin_amdgcn_sched_barrier(0);
    {
      const uint4 a0 = Ab[buf][arB][lk ^ (arB & 7)];
      const uint4 a1 = Ab[buf][arB][(4 + lk) ^ (arB & 7)];
      const uint4 b00 = Bb[buf][c0][lk ^ (c0 & 7)];
      const uint4 b01 = Bb[buf][c1][lk ^ (c1 & 7)];
      const uint4 b02 = Bb[buf][c2][lk ^ (c2 & 7)];
      const uint4 b03 = Bb[buf][c3][lk ^ (c3 & 7)];
      acc0 = __builtin_amdgcn_mfma_f32_16x16x32_bf16(as_s8(a0), as_s8(b00), acc0, 0, 0, 0);
      acc1 = __builtin_amdgcn_mfma_f32_16x16x32_bf16(as_s8(a0), as_s8(b01), acc1, 0, 0, 0);
      acc2 = __builtin_amdgcn_mfma_f32_16x16x32_bf16(as_s8(a0), as_s8(b02), acc2, 0, 0, 0);
      acc3 = __builtin_amdgcn_mfma_f32_16x16x32_bf16(as_s8(a0), as_s8(b03), acc3, 0, 0, 0);
      const uint4 b10 = Bb[buf][c0][(4 + lk) ^ (c0 & 7)];
      const uint4 b11 = Bb[buf][c1][(4 + lk) ^ (c1 & 7)];
      const uint4 b12 = Bb[buf][c2][(4 + lk) ^ (c2 & 7)];
      const uint4 b13 = Bb[buf][c3][(4 + lk) ^ (c3 & 7)];
      acc0 = __builtin_amdgcn_mfma_f32_16x16x32_bf16(as_s8(a1), as_s8(b10), acc0, 0, 0, 0);
      acc1 = __builtin_amdgcn_mfma_f32_16x16x32_bf16(as_s8(a1), as_s8(b11), acc1, 0, 0, 0);
      acc2 = __builtin_amdgcn_mfma_f32_16x16x32_bf16(as_s8(a1), as_s8(b12), acc2, 0, 0, 0);
      acc3 = __builtin_amdgcn_mfma_f32_16x16x32_bf16(as_s8(a1), as_s8(b13), acc3, 0, 0, 0);
    }
    {
      const uint4 u4 = Ab[buf][brow][(jj >> 1) ^ (brow & 7)];
      const uint2 u = (jj & 1) ? make_uint2(u4.z, u4.w) : make_uint2(u4.x, u4.y);
      float4 v;
      v.x = bf2f((unsigned short)(u.x & 0xffffu)) * il_brow;
      v.y = bf2f((unsigned short)(u.x >> 16)) * il_brow;
      v.z = bf2f((unsigned short)(u.y & 0xffffu)) * il_brow;
      v.w = bf2f((unsigned short)(u.y >> 16)) * il_brow;
      *reinterpret_cast<float4*>(beta + (size_t)(b * NPOS + row0 + brow) * NPOS +
                                 khalf * 2048 + kt * 64 + jj * 4) = v;
    }
    asm volatile("s_waitcnt vmcnt(1) lgkmcnt(0)\ns_barrier" ::: "memory");
    buf ^= 1;
  }
#undef STAGEB

  const float gam = gamma[0];
  if (opart) {
    float* op = opart + (size_t)khalf * 2 * NPOS * CDIM;
#pragma unroll
    for (int r = 0; r < 4; ++r) {
      const int lrr = wrB * 16 + lk * 4 + r;
      const int orow = row0 + lrr;
      const float sc = gam * linvB[lrr];
      float* o = op + ((size_t)b * NPOS + orow) * CDIM + wcB * 64 + lr;
      o[0] = sc * acc0[r];
      o[16] = sc * acc1[r];
      o[32] = sc * acc2[r];
      o[48] = sc * acc3[r];
    }
  } else {
#pragma unroll
    for (int r = 0; r < 4; ++r) {
      const int lrr = wrB * 16 + lk * 4 + r;
      const int orow = row0 + lrr;
      const float sc = gam * linvB[lrr];
      float* o = out + ((size_t)b * NPOS + orow) * CDIM + wcB * 64 + lr;
      atomicAdd(o, sc * acc0[r]);
      atomicAdd(o + 16, sc * acc1[r]);
      atomicAdd(o + 32, sc * acc2[r]);
      atomicAdd(o + 48, sc * acc3[r]);
    }
  }
}

// ---------------------------------------------------------------------------
// Kernel 3: out = x + p0 + p1.
// ---------------------------------------------------------------------------
__global__ __launch_bounds__(256) void reduce_out_kernel(
    const float* __restrict__ x, const float* __restrict__ opart,
    float* __restrict__ out) {
  const size_t i = ((size_t)blockIdx.x * 256 + threadIdx.x) * 4;
  const float4 xv = *reinterpret_cast<const float4*>(x + i);
  const float4 a = *reinterpret_cast<const float4*>(opart + i);
  const float4 bq = *reinterpret_cast<const float4*>(opart + (size_t)2 * NPOS * CDIM + i);
  float4 r;
  r.x = xv.x + a.x + bq.x;
  r.y = xv.y + a.y + bq.y;
  r.z = xv.z + a.z + bq.z;
  r.w = xv.w + a.w + bq.w;
  *reinterpret_cast<float4*>(out + i) = r;
}

// ---------------------------------------------------------------------------
// FALLBACK (ws too small): r14 fused kernel, P inside beta rows.
// ---------------------------------------------------------------------------
__global__ __launch_bounds__(1024, 4) void attn_fused_kernel(
    const unsigned short* __restrict__ f_hi, const unsigned short* __restrict__ f_lo,
    const unsigned short* __restrict__ g_hi, const unsigned short* __restrict__ g_lo,
    const unsigned short* __restrict__ h_t, const float* __restrict__ x,
    const float* __restrict__ gamma, float* __restrict__ beta,
    float* __restrict__ out) {
  __shared__ __align__(16) char shraw[110592];
  __shared__ float partl[16][16];
  __shared__ float linvs[32];
  uint4 (*Fh)[128][8] = reinterpret_cast<uint4(*)[128][8]>(shraw);
  uint4 (*Fl)[128][8] = reinterpret_cast<uint4(*)[128][8]>(shraw + 32768);
  uint4 (*Ab)[32][8] = reinterpret_cast<uint4(*)[32][8]>(shraw);
  uint4 (*Bb)[256][8] = reinterpret_cast<uint4(*)[256][8]>(shraw + 12288);

  const int wg = blockIdx.x;
  const int wgid = (wg & 7) * 32 + (wg >> 3);
  const int b = wgid >> 7;
  const int row0 = (wgid & 127) * 32;
  const int t = threadIdx.x;
  const int w = t >> 6;
  const int l = t & 63;
  const int lr = l & 15;
  const int lk = l >> 4;

  const int wr = w >> 3;
  const int wq = w & 7;
  const int arow = row0 + wr * 16 + lr;
  short8 gh[2], gl[2];
  {
    const unsigned short* gH = g_hi + ((size_t)(b * NPOS + arow)) * FDIM + lk * 8;
    const unsigned short* gL = g_lo + ((size_t)(b * NPOS + arow)) * FDIM + lk * 8;
#pragma unroll
    for (int ks = 0; ks < 2; ++ks) {
      gh[ks] = *reinterpret_cast<const short8*>(gH + ks * 32);
      gl[ks] = *reinterpret_cast<const short8*>(gL + ks * 32);
    }
  }
  const unsigned short* fbh = f_hi + (size_t)b * NPOS * FDIM;
  const unsigned short* fbl = f_lo + (size_t)b * NPOS * FDIM;
  unsigned short* Pb = (unsigned short*)(beta + (size_t)b * NPOS * NPOS);
  unsigned short* prow = Pb + (size_t)arow * (2 * NPOS) + NPOS;
  const int rsw = lr & 7;
  float lsum = 0.f;
  const int srow_ = t >> 3, sch_ = t & 7;

#define STAGEA(buf, tile)                                                      \
  do {                                                                         \
    const int tr_ = (tile) * 128 + srow_;                                      \
    gload_lds16(fbh + (size_t)tr_ * FDIM + sch_ * 8,                           \
                (char*)&Fh[buf][0][0] + (size_t)t * 16);                       \
    gload_lds16(fbl + (size_t)tr_ * FDIM + sch_ * 8,                           \
                (char*)&Fl[buf][0][0] + (size_t)t * 16);                       \
  } while (0)

  STAGEA(0, 0);
  asm volatile("s_waitcnt vmcnt(0) lgkmcnt(0)\ns_barrier" ::: "memory");

  const int rrA = wq * 16 + lr;
  const int fsw = rrA & 7;
  int buf = 0;
  for (int tile = 0; tile < 32; ++tile) {
    if (tile < 31) STAGEA(buf ^ 1, tile + 1);
    __builtin_amdgcn_sched_barrier(0);
    const uint4 h0 = Fh[buf][rrA][lk ^ fsw];
    const uint4 h1 = Fh[buf][rrA][(lk + 4) ^ fsw];
    const uint4 q0 = Fl[buf][rrA][lk ^ fsw];
    const uint4 q1 = Fl[buf][rrA][(lk + 4) ^ fsw];
    f32x4 acca = {0.f, 0.f, 0.f, 0.f};
    f32x4 accb = {0.f, 0.f, 0.f, 0.f};
    acca = __builtin_amdgcn_mfma_f32_16x16x32_bf16(as_s8(h0), gh[0], acca, 0, 0, 0);
    accb = __builtin_amdgcn_mfma_f32_16x16x32_bf16(as_s8(h0), gl[0], accb, 0, 0, 0);
    acca = __builtin_amdgcn_mfma_f32_16x16x32_bf16(as_s8(q0), gh[0], acca, 0, 0, 0);
    accb = __builtin_amdgcn_mfma_f32_16x16x32_bf16(as_s8(h1), gh[1], accb, 0, 0, 0);
    acca = __builtin_amdgcn_mfma_f32_16x16x32_bf16(as_s8(q1), gh[1], acca, 0, 0, 0);
    accb = __builtin_amdgcn_mfma_f32_16x16x32_bf16(as_s8(h1), gl[1], accb, 0, 0, 0);
    const f32x4 acc = acca + accb;
    const int cq = tile * 128 + wq * 16 + lk * 4;
    const float e0 = __expf(acc[0]);
    const float e1 = __expf(acc[1]);
    const float e2 = __expf(acc[2]);
    const float e3 = __expf(acc[3]);
    lsum += (e0 + e1) + (e2 + e3);
    uint2 pk;
    pk.x = (unsigned)f2bf(e0) | ((unsigned)f2bf(e1) << 16);
    pk.y = (unsigned)f2bf(e2) | ((unsigned)f2bf(e3) << 16);
    const int sidx = (((cq >> 3) ^ rsw) << 3) | (cq & 7);
    *reinterpret_cast<uint2*>(prow + sidx) = pk;
    asm volatile("s_waitcnt vmcnt(1) lgkmcnt(0)\ns_barrier" ::: "memory");
    buf ^= 1;
  }
#undef STAGEA

  lsum += __shfl_xor(lsum, 16);
  lsum += __shfl_xor(lsum, 32);
  if (l < 16) partl[w][l] = lsum;
  __syncthreads();
  if (t < 32) {
    const int half = t >> 4;
    float s = 0.f;
#pragma unroll
    for (int q = 0; q < 8; ++q) s += partl[half * 8 + q][t & 15];
    linvs[t] = __frcp_rn(s);
  }
  asm volatile("s_waitcnt vmcnt(0) lgkmcnt(0)\ns_barrier" ::: "memory");

  const size_t hoff = (size_t)b * CDIM * NPOS;
  const unsigned short* Pub = (const unsigned short*)(beta + (size_t)b * NPOS * NPOS);

#define STAGEB(bufi, kt)                                                        \
  do {                                                                          \
    {                                                                           \
      const int slot_ = w * 128 + l;                                            \
      const unsigned short* g_ = h_t + hoff + (size_t)(slot_ >> 3) * NPOS +     \
                                 (size_t)((kt) * 8 + (slot_ & 7)) * 8;          \
      gload_lds16(g_, (unsigned short*)&Bb[bufi][0][0] + (size_t)(w * 128) * 8);\
    }                                                                           \
    {                                                                           \
      const int slot_ = w * 128 + 64 + l;                                       \
      const unsigned short* g_ = h_t + hoff + (size_t)(slot_ >> 3) * NPOS +     \
                                 (size_t)((kt) * 8 + (slot_ & 7)) * 8;          \
      gload_lds16(g_, (unsigned short*)&Bb[bufi][0][0] +                        \
                          (size_t)(w * 128 + 64) * 8);                          \
    }                                                                           \
    if (t < 256) {                                                              \
      const unsigned short* g_ = Pub + (size_t)(row0 + (t >> 3)) * (2 * NPOS) + \
                                 NPOS + (size_t)((kt) * 8 + (t & 7)) * 8;       \
      gload_lds16(g_, (unsigned short*)&Ab[bufi][0][0] + (size_t)(w * 64) * 8); \
    }                                                                           \
  } while (0)

  f32x4 acc0 = {0.f, 0.f, 0.f, 0.f}, acc1 = {0.f, 0.f, 0.f, 0.f};
  const int wrB = w & 1;
  const int wcB = w >> 1;
  const int arB = wrB * 16 + lr;
  const int c0 = wcB * 32 + lr;
  const int c1 = c0 + 16;
  const int brow = t >> 5;
  const int jj = t & 31;
  const float il_brow = linvs[brow];

  STAGEB(0, 0);
  asm volatile("s_waitcnt vmcnt(0) lgkmcnt(0)\ns_barrier" ::: "memory");

  buf = 0;
  for (int kt = 0; kt < 64; ++kt) {
    if (kt < 63) STAGEB(buf ^ 1, kt + 1);
    __builtin_amdgcn_sched_barrier(0);
    {
      const uint4 a0 = Ab[buf][arB][lk ^ (arB & 7)];
      const uint4 a1 = Ab[buf][arB][(4 + lk) ^ (arB & 7)];
      const uint4 b00 = Bb[buf][c0][lk ^ (c0 & 7)];
      const uint4 b01 = Bb[buf][c1][lk ^ (c1 & 7)];
      const uint4 b10 = Bb[buf][c0][(4 + lk) ^ (c0 & 7)];
      const uint4 b11 = Bb[buf][c1][(4 + lk) ^ (c1 & 7)];
      acc0 = __builtin_amdgcn_mfma_f32_16x16x32_bf16(as_s8(a0), as_s8(b00), acc0, 0, 0, 0);
      acc1 = __builtin_amdgcn_mfma_f32_16x16x32_bf16(as_s8(a0), as_s8(b01), acc1, 0, 0, 0);
      acc0 = __builtin_amdgcn_mfma_f32_16x16x32_bf16(as_s8(a1), as_s8(b10), acc0, 0, 0, 0);
      acc1 = __builtin_amdgcn_mfma_f32_16x16x32_bf16(as_s8(a1), as_s8(b11), acc1, 0, 0, 0);
    }
    {
      const unsigned* arow_ = reinterpret_cast<const unsigned*>(&Ab[buf][brow][0]);
      const unsigned u = arow_[(((jj >> 2) ^ (brow & 7)) << 2) | (jj & 3)];
      float2 v;
      v.x = bf2f((unsigned short)(u & 0xffffu)) * il_brow;
      v.y = bf2f((unsigned short)(u >> 16)) * il_brow;
      *reinterpret_cast<float2*>(beta + (size_t)(b * NPOS + row0 + brow) * NPOS +
                                 (size_t)kt * 64 + jj * 2) = v;
    }
    asm volatile("s_waitcnt vmcnt(1) lgkmcnt(0)\ns_barrier" ::: "memory");
    buf ^= 1;
  }
#undef STAGEB

  const float gam = gamma[0];
#pragma unroll
  for (int r = 0; r < 4; ++r) {
    const int lrr = wrB * 16 + lk * 4 + r;
    const int orow = row0 + lrr;
    const float sc = gam * linvs[lrr];
    const size_t i0 = ((size_t)b * NPOS + orow) * CDIM + wcB * 32 + lr;
    out[i0] = fmaf(sc, acc0[r], x[i0]);
    out[i0 + 16] = fmaf(sc, acc1[r], x[i0 + 16]);
  }
}

extern "C" void kernel_launch(void* const* d_in, const int* in_sizes, int n_in,
                              void* d_out, int out_size, void* d_ws, size_t ws_size,
                              hipStream_t stream) {
  (void)in_sizes; (void)n_in; (void)out_size;
  const float* x = (const float*)d_in[0];
  const float* Wf = (const float*)d_in[1];
  const float* Wg = (const float*)d_in[2];
  const float* Wh = (const float*)d_in[3];
  const float* gamma = (const float*)d_in[4];

  float* out = (float*)d_out;                                   // [2*4096*256]
  float* beta = out + (size_t)2 * NPOS * CDIM;                  // [2*4096*4096]

  unsigned short* h_t = (unsigned short*)d_ws;                  // [2*256*4096]
  unsigned short* f_hi = h_t + (size_t)2 * CDIM * NPOS;         // [8192*64] each
  unsigned short* f_lo = f_hi + (size_t)2 * NPOS * FDIM;
  unsigned short* g_hi = f_lo + (size_t)2 * NPOS * FDIM;
  unsigned short* g_lo = g_hi + (size_t)2 * NPOS * FDIM;
  float* lrow = (float*)(g_lo + (size_t)2 * NPOS * FDIM);       // [8192]
  unsigned short* WThi = (unsigned short*)(lrow + 2 * NPOS);    // [384*256]
  unsigned short* WTlo = WThi + (size_t)384 * 256;
  unsigned short* Pws = WTlo + (size_t)384 * 256;               // [2*4096*4096]
  float* opart = (float*)(Pws + (size_t)2 * NPOS * NPOS);       // [2][2*4096*256]

  const size_t need_full =
      ((char*)(opart + (size_t)4 * NPOS * CDIM)) - (char*)d_ws;

  if (ws_size >= need_full) {
    hipLaunchKernelGGL(wsplit_kernel, dim3(384), dim3(256), 0, stream,
                       Wf, Wg, Wh, WThi, WTlo);
    hipLaunchKernelGGL(proj_mfma_kernel, dim3(256), dim3(1024), 0, stream,
                       x, WThi, WTlo, f_hi, f_lo, g_hi, g_lo, h_t);
    hipLaunchKernelGGL(qk_l_kernel, dim3(256), dim3(1024), 0, stream,
                       f_hi, f_lo, g_hi, g_lo, Pws, lrow);
    hipLaunchKernelGGL(pv_split_kernel, dim3(256), dim3(1024), 0, stream,
                       h_t, Pws, lrow, gamma, beta, out, opart);
    hipLaunchKernelGGL(reduce_out_kernel, dim3(2 * NPOS * CDIM / 1024), dim3(256),
                       0, stream, x, opart, out);
  } else {
    hipLaunchKernelGGL(proj_kernel, dim3(2 * NPOS / 16), dim3(256), 0, stream,
                       x, Wf, Wg, Wh, f_hi, f_lo, g_hi, g_lo, h_t, out);
    hipLaunchKernelGGL(attn_fused_kernel, dim3(256), dim3(1024), 0, stream,
                       f_hi, f_lo, g_hi, g_lo, h_t, x, gamma, beta, out);
  }
}